// Round 12
// baseline (758.186 us; speedup 1.0000x reference)
//
#include <hip/hip_runtime.h>
#include <hip/hip_bf16.h>
#include <stdint.h>

#define NF 165
#define NH 128
#define KP 192          // padded K for MFMA
#define NCOLS 384
#define BSH 8           // rows per bucket = 256
#define BROWS 256
#define BCAP 6144       // whole-bucket capacity for emit LDS buffer
#define NSUB 8          // sub-buckets per bucket (one per XCD)
#define BSUBCAP 768     // per-(bucket,xcd) capacity (mean 512, +11 sigma)
#define CPAD 16         // cursor padding: 16 ints = 64B line

typedef __attribute__((ext_vector_type(8))) short bf16x8;
typedef __attribute__((ext_vector_type(4))) float f32x4;

// ---- bf16 helpers --------------------------------------------------------

__device__ __forceinline__ unsigned short f2bf(float f) {
    unsigned int u = __builtin_bit_cast(unsigned int, f);
    u = (u + 0x7FFFu + ((u >> 16) & 1u)) >> 16;   // RNE
    return (unsigned short)u;
}
__device__ __forceinline__ float bf2f_lo(unsigned int v) {
    return __builtin_bit_cast(float, v << 16);
}
__device__ __forceinline__ float bf2f_hi(unsigned int v) {
    return __builtin_bit_cast(float, v & 0xFFFF0000u);
}

// ---- CSR build ----------------------------------------------------------

// Level-1: append edges to XCD-local sub-buckets. NT loads keep the 25.6MB
// edge stream OUT of L2 so sub-bucket head lines + cursors stay resident ->
// full-line writebacks (r11: head lines were evicted by this very stream).
__global__ __launch_bounds__(256) void k_bucket(
        const int* __restrict__ erow, const int* __restrict__ ecol,
        int* __restrict__ bcur, unsigned int* __restrict__ bkt, int E) {
    int e = blockIdx.x * 256 + threadIdx.x;
    if (e >= E) return;
    int x = blockIdx.x & (NSUB - 1);
    int r = __builtin_nontemporal_load(erow + e);
    int c = __builtin_nontemporal_load(ecol + e);
    int sub = (r >> BSH) * NSUB + x;
    int pos = atomicAdd(&bcur[sub * CPAD], 1);
    if (pos < BSUBCAP)
        bkt[(size_t)sub * BSUBCAP + pos] =
            ((unsigned)(r & (BROWS - 1)) << 18) | (unsigned)c;
}

// Histogram bucket records -> cnt + dis (fused).
__global__ __launch_bounds__(256) void k_hist(
        const int* __restrict__ bcur, const unsigned int* __restrict__ bkt,
        int* __restrict__ cnt, float* __restrict__ dis, int N) {
    __shared__ int h[BROWS];
    int b = blockIdx.x;
    int t = threadIdx.x;
    h[t] = 0;
    __syncthreads();
#pragma unroll
    for (int x = 0; x < NSUB; ++x) {
        int sub = b * NSUB + x;
        int nb = bcur[sub * CPAD];
        if (nb > BSUBCAP) nb = BSUBCAP;
        const unsigned int* src = bkt + (size_t)sub * BSUBCAP;
        for (int i = t; i < nb; i += 256)
            atomicAdd(&h[__builtin_nontemporal_load(src + i) >> 18], 1);
    }
    __syncthreads();
    int base = b << BSH;
    if (base + t < N) {
        int d = h[t];
        cnt[base + t] = d;
        dis[base + t] = (d > 0) ? rsqrtf((float)d) : 0.0f;
    }
}

__global__ __launch_bounds__(256) void k_scan1(
        const int* __restrict__ cnt, int* __restrict__ off,
        int* __restrict__ bsum, int N) {
    __shared__ int sh[256];
    int t = threadIdx.x;
    int base = blockIdx.x * 1024 + t * 4;
    int v0 = (base + 0 < N) ? cnt[base + 0] : 0;
    int v1 = (base + 1 < N) ? cnt[base + 1] : 0;
    int v2 = (base + 2 < N) ? cnt[base + 2] : 0;
    int v3 = (base + 3 < N) ? cnt[base + 3] : 0;
    int tsum = v0 + v1 + v2 + v3;
    sh[t] = tsum;
    __syncthreads();
#pragma unroll
    for (int ofs = 1; ofs < 256; ofs <<= 1) {
        int x = (t >= ofs) ? sh[t - ofs] : 0;
        __syncthreads();
        sh[t] += x;
        __syncthreads();
    }
    int excl = sh[t] - tsum;
    if (t == 255) bsum[blockIdx.x] = sh[t];
    if (base + 0 < N) off[base + 0] = excl;
    excl += v0;
    if (base + 1 < N) off[base + 1] = excl;
    excl += v1;
    if (base + 2 < N) off[base + 2] = excl;
    excl += v2;
    if (base + 3 < N) off[base + 3] = excl;
}

__global__ __launch_bounds__(256) void k_scan2(int* __restrict__ bsum, int NB) {
    __shared__ int sh[256];
    int t = threadIdx.x;
    int v = (t < NB) ? bsum[t] : 0;
    sh[t] = v;
    __syncthreads();
#pragma unroll
    for (int ofs = 1; ofs < 256; ofs <<= 1) {
        int x = (t >= ofs) ? sh[t - ofs] : 0;
        __syncthreads();
        sh[t] += x;
        __syncthreads();
    }
    if (t < NB) bsum[t] = sh[t] - v;
}

__global__ __launch_bounds__(256) void k_scan3(
        int* __restrict__ off, const int* __restrict__ bsum, int N, int E) {
    int i = blockIdx.x * 256 + threadIdx.x;
    if (i >= N) return;
    off[i] = off[i] + bsum[i >> 10];
    if (i == 0) off[N] = E;
}

// Level-2: one block per bucket; place edges at exact CSR slots via LDS,
// then stream out coalesced (nt-store: scol is write-once).
__global__ __launch_bounds__(256) void k_emit(
        const int* __restrict__ bcur, const unsigned int* __restrict__ bkt,
        const int* __restrict__ off, int* __restrict__ scol, int N) {
    __shared__ unsigned colbuf[BCAP];
    __shared__ int rowoff[BROWS + 1];
    __shared__ int cursor[BROWS];

    int b = blockIdx.x;
    int base = b << BSH;
    int nrows = N - base;
    if (nrows > BROWS) nrows = BROWS;
    int t = threadIdx.x;

    for (int i = t; i <= nrows; i += 256) rowoff[i] = off[base + i];
    if (t < BROWS) cursor[t] = 0;
    __syncthreads();

    int regionStart = rowoff[0];
    int total = rowoff[nrows] - regionStart;

#pragma unroll
    for (int x = 0; x < NSUB; ++x) {
        int sub = b * NSUB + x;
        int nb = bcur[sub * CPAD];
        if (nb > BSUBCAP) nb = BSUBCAP;
        const unsigned int* src = bkt + (size_t)sub * BSUBCAP;
        for (int i = t; i < nb; i += 256) {
            unsigned v = __builtin_nontemporal_load(src + i);
            int rl = v >> 18;
            unsigned c = v & 0x3FFFFu;
            int pos = (rowoff[rl] - regionStart) + atomicAdd(&cursor[rl], 1);
            if (pos < BCAP) colbuf[pos] = c;
        }
    }
    __syncthreads();

    for (int i = t; i < total; i += 256)
        __builtin_nontemporal_store((int)colbuf[i], scol + regionStart + i);
}

// ---- conversions ---------------------------------------------------------

__global__ __launch_bounds__(256) void k_xb(
        const float* __restrict__ x, unsigned short* __restrict__ xb, int N) {
    int gid = blockIdx.x * 256 + threadIdx.x;
    if (gid >= N * (KP / 8)) return;
    int row = gid / (KP / 8);
    int k0 = (gid % (KP / 8)) * 8;
    unsigned short v[8];
#pragma unroll
    for (int i = 0; i < 8; ++i) {
        int k = k0 + i;
        v[i] = (k < NF) ? f2bf(x[(size_t)row * NF + k]) : (unsigned short)0;
    }
    uint4 pk;
    pk.x = (unsigned)v[0] | ((unsigned)v[1] << 16);
    pk.y = (unsigned)v[2] | ((unsigned)v[3] << 16);
    pk.z = (unsigned)v[4] | ((unsigned)v[5] << 16);
    pk.w = (unsigned)v[6] | ((unsigned)v[7] << 16);
    *(uint4*)(xb + (size_t)row * KP + k0) = pk;
}

__global__ __launch_bounds__(256) void k_wbt(
        const float* __restrict__ W1, unsigned short* __restrict__ wbt) {
    int gid = blockIdx.x * 256 + threadIdx.x;
    if (gid >= NCOLS * (KP / 8)) return;
    int col = gid / (KP / 8);
    int k0 = (gid % (KP / 8)) * 8;
    int cc = col & 127;
    unsigned short v[8];
#pragma unroll
    for (int i = 0; i < 8; ++i) {
        int k = k0 + i;
        float f = 0.0f;
        if (k < NF) {
            if (col < 128)      f = W1[k * 128 + cc] - W1[42240 + k * 128 + cc];
            else if (col < 256) f = W1[21120 + k * 128 + cc];
            else                f = W1[42240 + k * 128 + cc];
        }
        v[i] = f2bf(f);
    }
    uint4 pk;
    pk.x = (unsigned)v[0] | ((unsigned)v[1] << 16);
    pk.y = (unsigned)v[2] | ((unsigned)v[3] << 16);
    pk.z = (unsigned)v[4] | ((unsigned)v[5] << 16);
    pk.w = (unsigned)v[6] | ((unsigned)v[7] << 16);
    *(uint4*)(wbt + (size_t)col * KP + k0) = pk;
}

// Wc2[128][8] with k in interleaved-hidden layout: k_lin 2c->(c), 2c+1->(c+64)
__global__ __launch_bounds__(256) void k_wc2(const float* __restrict__ W2,
                                             float* __restrict__ Wc2) {
    int gid = blockIdx.x * 256 + threadIdx.x;
    if (gid >= 128 * 8) return;
    int k = gid >> 3;
    int c = gid & 7;
    int ko = (k & 1) ? (k >> 1) + 64 : (k >> 1);
    float v = 0.0f;
    if (c < 2)      v = W2[ko * 2 + c] - W2[512 + ko * 2 + c];
    else if (c < 4) v = W2[256 + ko * 2 + (c - 2)];
    else if (c < 6) v = W2[512 + ko * 2 + (c - 4)];
    Wc2[gid] = v;
}

// ---- GEMM1 via MFMA ------------------------------------------------------
// g==0 -> ub = u (bf16); g==1 -> sA = dis*s (bf16); g==2 -> wb = dis*w (bf16)
__global__ __launch_bounds__(256) void k_gemm1_mfma(
        const unsigned short* __restrict__ xb, const unsigned short* __restrict__ wbt,
        const float* __restrict__ dis,
        unsigned int* __restrict__ ub, unsigned int* __restrict__ sA,
        unsigned int* __restrict__ wb, int N) {
    __shared__ unsigned short As[128][40];
    __shared__ unsigned short Bs[128][40];

    int tid = threadIdx.x;
    int w = tid >> 6;
    int lane = tid & 63;
    int l15 = lane & 15;
    int l16 = lane >> 4;
    int g = blockIdx.x;
    int brow = blockIdx.y * 128;
    int gcol = g * 128;

    int sr = tid >> 1;
    int sk = (tid & 1) * 16;

    f32x4 acc[2][8] = {};

    for (int kc = 0; kc < 6; ++kc) {
        int k0 = kc * 32;
        uint4 va0 = {0, 0, 0, 0}, va1 = {0, 0, 0, 0};
        if (brow + sr < N) {
            const unsigned short* asrc = xb + (size_t)(brow + sr) * KP + k0 + sk;
            va0 = *(const uint4*)asrc;
            va1 = *(const uint4*)(asrc + 8);
        }
        const unsigned short* bsrc = wbt + (size_t)(gcol + sr) * KP + k0 + sk;
        uint4 vb0 = *(const uint4*)bsrc;
        uint4 vb1 = *(const uint4*)(bsrc + 8);
        __syncthreads();
        *(uint4*)&As[sr][sk] = va0;
        *(uint4*)&As[sr][sk + 8] = va1;
        *(uint4*)&Bs[sr][sk] = vb0;
        *(uint4*)&Bs[sr][sk + 8] = vb1;
        __syncthreads();

        bf16x8 a[2], b[8];
#pragma unroll
        for (int m = 0; m < 2; ++m)
            a[m] = *(const bf16x8*)&As[w * 32 + m * 16 + l15][l16 * 8];
#pragma unroll
        for (int n = 0; n < 8; ++n)
            b[n] = *(const bf16x8*)&Bs[n * 16 + l15][l16 * 8];
#pragma unroll
        for (int m = 0; m < 2; ++m)
#pragma unroll
            for (int n = 0; n < 8; ++n)
                acc[m][n] = __builtin_amdgcn_mfma_f32_16x16x32_bf16(
                    a[m], b[n], acc[m][n], 0, 0, 0);
    }

    unsigned int* dst = (g == 0) ? ub : (g == 1) ? sA : wb;
#pragma unroll
    for (int m = 0; m < 2; ++m) {
#pragma unroll
        for (int reg = 0; reg < 4; ++reg) {
            int row = brow + w * 32 + m * 16 + l16 * 4 + reg;
            if (row >= N) continue;
            float sc = (g == 0) ? 1.0f : dis[row];
#pragma unroll
            for (int n = 0; n < 4; ++n) {
                int c = n * 16 + l15;
                float lo = sc * acc[m][n][reg];
                float hi = sc * acc[m][n + 4][reg];
                dst[(size_t)row * 64 + c] =
                    (unsigned)f2bf(lo) | ((unsigned)f2bf(hi) << 16);
            }
        }
    }
}

// ---- 128-wide props: 4 rows/wave, 16 lanes/row, uint4 gathers, unroll-2 ---

// sb[r] = bf16( sA[r] - 2*dis[r]^2 * sum_e wb[col] )
__global__ __launch_bounds__(256) void k_prop_b2b(
        const int* __restrict__ off, const int* __restrict__ scol,
        const unsigned int* __restrict__ srcb, const unsigned int* __restrict__ addb,
        const float* __restrict__ dis, unsigned int* __restrict__ dstb, int N) {
    int wid = (blockIdx.x * 256 + threadIdx.x) >> 6;
    int lane = threadIdx.x & 63;
    int g = lane >> 4, q = lane & 15;
    int r = wid * 4 + g;
    if (r >= N) return;
    int e = off[r], end = off[r + 1];
    const uint4* src4 = (const uint4*)srcb;
    float a[8] = {}, b[8] = {};
    for (; e + 2 <= end; e += 2) {
        int c0 = __builtin_nontemporal_load(scol + e);
        int c1 = __builtin_nontemporal_load(scol + e + 1);
        uint4 v0 = src4[(size_t)c0 * 16 + q];
        uint4 v1 = src4[(size_t)c1 * 16 + q];
        unsigned vv0[4] = {v0.x, v0.y, v0.z, v0.w};
        unsigned vv1[4] = {v1.x, v1.y, v1.z, v1.w};
#pragma unroll
        for (int j = 0; j < 4; ++j) {
            a[2 * j] += bf2f_lo(vv0[j]); a[2 * j + 1] += bf2f_hi(vv0[j]);
            b[2 * j] += bf2f_lo(vv1[j]); b[2 * j + 1] += bf2f_hi(vv1[j]);
        }
    }
    if (e < end) {
        int c0 = __builtin_nontemporal_load(scol + e);
        uint4 v0 = src4[(size_t)c0 * 16 + q];
        unsigned vv0[4] = {v0.x, v0.y, v0.z, v0.w};
#pragma unroll
        for (int j = 0; j < 4; ++j) {
            a[2 * j] += bf2f_lo(vv0[j]); a[2 * j + 1] += bf2f_hi(vv0[j]);
        }
    }
    float d = dis[r];
    float m2 = -2.0f * d * d;
    uint4 ad = ((const uint4*)addb)[(size_t)r * 16 + q];
    unsigned adp[4] = {ad.x, ad.y, ad.z, ad.w};
    uint4 o;
    unsigned* op = (unsigned*)&o;
#pragma unroll
    for (int j = 0; j < 4; ++j) {
        float lo = bf2f_lo(adp[j]) + m2 * (a[2 * j] + b[2 * j]);
        float hi = bf2f_hi(adp[j]) + m2 * (a[2 * j + 1] + b[2 * j + 1]);
        op[j] = (unsigned)f2bf(lo) | ((unsigned)f2bf(hi) << 16);
    }
    ((uint4*)dstb)[(size_t)r * 16 + q] = o;
}

// hb[r] = bf16( relu( ub[r] - dis[r] * sum_e sb[col] + b1 ) )
__global__ __launch_bounds__(256) void k_prop_b2f_relu(
        const int* __restrict__ off, const int* __restrict__ scol,
        const unsigned int* __restrict__ srcb, const unsigned int* __restrict__ addb,
        const float* __restrict__ dis, const float* __restrict__ b1,
        unsigned int* __restrict__ hb, int N) {
    int wid = (blockIdx.x * 256 + threadIdx.x) >> 6;
    int lane = threadIdx.x & 63;
    int g = lane >> 4, q = lane & 15;
    int r = wid * 4 + g;
    if (r >= N) return;
    int e = off[r], end = off[r + 1];
    const uint4* src4 = (const uint4*)srcb;
    float a[8] = {}, b[8] = {};
    for (; e + 2 <= end; e += 2) {
        int c0 = __builtin_nontemporal_load(scol + e);
        int c1 = __builtin_nontemporal_load(scol + e + 1);
        uint4 v0 = src4[(size_t)c0 * 16 + q];
        uint4 v1 = src4[(size_t)c1 * 16 + q];
        unsigned vv0[4] = {v0.x, v0.y, v0.z, v0.w};
        unsigned vv1[4] = {v1.x, v1.y, v1.z, v1.w};
#pragma unroll
        for (int j = 0; j < 4; ++j) {
            a[2 * j] += bf2f_lo(vv0[j]); a[2 * j + 1] += bf2f_hi(vv0[j]);
            b[2 * j] += bf2f_lo(vv1[j]); b[2 * j + 1] += bf2f_hi(vv1[j]);
        }
    }
    if (e < end) {
        int c0 = __builtin_nontemporal_load(scol + e);
        uint4 v0 = src4[(size_t)c0 * 16 + q];
        unsigned vv0[4] = {v0.x, v0.y, v0.z, v0.w};
#pragma unroll
        for (int j = 0; j < 4; ++j) {
            a[2 * j] += bf2f_lo(vv0[j]); a[2 * j + 1] += bf2f_hi(vv0[j]);
        }
    }
    float m1 = -dis[r];
    uint4 ad = ((const uint4*)addb)[(size_t)r * 16 + q];
    unsigned adp[4] = {ad.x, ad.y, ad.z, ad.w};
    uint4 o;
    unsigned* op = (unsigned*)&o;
#pragma unroll
    for (int j = 0; j < 4; ++j) {
        int c = q * 4 + j;
        float lo = fmaxf(bf2f_lo(adp[j]) + m1 * (a[2 * j] + b[2 * j]) + b1[c], 0.0f);
        float hi = fmaxf(bf2f_hi(adp[j]) + m1 * (a[2 * j + 1] + b[2 * j + 1]) + b1[c + 64], 0.0f);
        op[j] = (unsigned)f2bf(lo) | ((unsigned)f2bf(hi) << 16);
    }
    ((uint4*)hb)[(size_t)r * 16 + q] = o;
}

// GEMM2: hb[N,64] (bf16 pairs) @ Wc2[128,8] -> out(+b2) f32, s2=dis*s2raw, w2=dis*w2raw
__global__ __launch_bounds__(256) void k_gemm2(
        const unsigned int* __restrict__ hb, const float* __restrict__ Wc2,
        const float* __restrict__ b2, const float* __restrict__ dis,
        float* __restrict__ out, float* __restrict__ s2, float* __restrict__ w2,
        int N) {
    __shared__ float Ws[128 * 8];
    int tid = threadIdx.x;
    for (int idx = tid; idx < 128 * 8; idx += 256) Ws[idx] = Wc2[idx];
    __syncthreads();

    int rl = tid >> 3;
    int sub = tid & 7;
    int row = blockIdx.x * 32 + rl;
    if (row >= N) return;

    float4 accA = {0, 0, 0, 0};
    float4 accB = {0, 0, 0, 0};
    const uint4* hp = (const uint4*)(hb + (size_t)row * 64 + sub * 8);
#pragma unroll
    for (int qq = 0; qq < 2; ++qq) {
        uint4 hv = hp[qq];
        unsigned hu[4] = {hv.x, hv.y, hv.z, hv.w};
#pragma unroll
        for (int t = 0; t < 4; ++t) {
            int kl = sub * 16 + qq * 8 + 2 * t;
            float he0 = bf2f_lo(hu[t]);
            float he1 = bf2f_hi(hu[t]);
            const float* w0 = &Ws[kl * 8];
            const float* w1 = &Ws[(kl + 1) * 8];
            accA.x += he0 * w0[0] + he1 * w1[0];
            accA.y += he0 * w0[1] + he1 * w1[1];
            accA.z += he0 * w0[2] + he1 * w1[2];
            accA.w += he0 * w0[3] + he1 * w1[3];
            accB.x += he0 * w0[4] + he1 * w1[4];
            accB.y += he0 * w0[5] + he1 * w1[5];
        }
    }
#pragma unroll
    for (int off = 4; off; off >>= 1) {
        accA.x += __shfl_xor(accA.x, off);
        accA.y += __shfl_xor(accA.y, off);
        accA.z += __shfl_xor(accA.z, off);
        accA.w += __shfl_xor(accA.w, off);
        accB.x += __shfl_xor(accB.x, off);
        accB.y += __shfl_xor(accB.y, off);
    }
    if (sub == 0) {
        float d = dis[row];
        out[(size_t)row * 2 + 0] = accA.x + b2[0];
        out[(size_t)row * 2 + 1] = accA.y + b2[1];
        s2[(size_t)row * 2 + 0] = d * accA.z;
        s2[(size_t)row * 2 + 1] = d * accA.w;
        w2[(size_t)row * 2 + 0] = d * accB.x;
        w2[(size_t)row * 2 + 1] = d * accB.y;
    }
}

// CSR prop, 2-wide: dst[r] = add[r] + m * sum src[col], m = sq ? -2*dis^2 : -dis.
__global__ __launch_bounds__(256) void k_prop2_csr(
        const int* __restrict__ off, const int* __restrict__ scol,
        const float* __restrict__ src, const float* __restrict__ add,
        const float* __restrict__ dis, float* __restrict__ dst,
        int sq, int N) {
    int r = blockIdx.x * 256 + threadIdx.x;
    if (r >= N) return;
    int e0 = off[r], e1 = off[r + 1];
    float a0 = 0.0f, a1 = 0.0f;
    for (int e = e0; e < e1; ++e) {
        int c = __builtin_nontemporal_load(scol + e);
        float2 v = *(const float2*)(src + (size_t)c * 2);
        a0 += v.x;
        a1 += v.y;
    }
    float d = dis[r];
    float m = sq ? (-2.0f * d * d) : (-d);
    float2 ad = *(const float2*)(add + (size_t)r * 2);
    float2 o = {ad.x + m * a0, ad.y + m * a1};
    *(float2*)(dst + (size_t)r * 2) = o;
}

extern "C" void kernel_launch(void* const* d_in, const int* in_sizes, int n_in,
                              void* d_out, int out_size, void* d_ws, size_t ws_size,
                              hipStream_t stream) {
    const float* x   = (const float*)d_in[0];
    const int* eidx  = (const int*)d_in[1];
    const float* W1  = (const float*)d_in[2];
    const float* b1  = (const float*)d_in[3];
    const float* W2  = (const float*)d_in[4];
    const float* b2  = (const float*)d_in[5];
    float* out       = (float*)d_out;

    int N = in_sizes[0] / NF;
    int E = in_sizes[1] / 2;
    const int* erow = eidx;
    const int* ecol = eidx + E;
    int NBK = (N + BROWS - 1) >> BSH;

    char* p = (char*)d_ws;
    auto alloc = [&](size_t bytes) {
        char* q = p;
        p += (bytes + 255) & ~(size_t)255;
        return q;
    };
    unsigned int* ub = (unsigned int*)alloc((size_t)N * 64 * 4);
    unsigned int* sA = (unsigned int*)alloc((size_t)N * 64 * 4);
    unsigned int* wb = (unsigned int*)alloc((size_t)N * 64 * 4);  // reused as hb
    unsigned int* sb = (unsigned int*)alloc((size_t)N * 64 * 4);
    unsigned short* xb  = (unsigned short*)alloc((size_t)N * KP * 2);
    unsigned short* wbt = (unsigned short*)alloc((size_t)NCOLS * KP * 2);
    float* dis  = (float*)alloc((size_t)N * 4);
    int* cnt    = (int*)alloc((size_t)N * 4);
    int* off    = (int*)alloc((size_t)(N + 1) * 4);
    int* bsum   = (int*)alloc((size_t)256 * 4);
    int* bcur   = (int*)alloc((size_t)NBK * NSUB * CPAD * 4);
    unsigned int* bkt = (unsigned int*)alloc((size_t)NBK * NSUB * BSUBCAP * 4);
    int* scol   = (int*)alloc((size_t)E * 4);
    float* Wc2  = (float*)alloc((size_t)128 * 8 * 4);
    float* s2   = (float*)alloc((size_t)N * 2 * 4);
    float* w2   = (float*)alloc((size_t)N * 2 * 4);

    hipMemsetAsync(bcur, 0, (size_t)NBK * NSUB * CPAD * 4, stream);

    int gE = (E + 255) / 256;
    int gN = (N + 255) / 256;
    int NB = (N + 1023) / 1024;

    // conversions
    k_xb<<<(N * (KP / 8) + 255) / 256, 256, 0, stream>>>(x, xb, N);
    k_wbt<<<(NCOLS * (KP / 8) + 255) / 256, 256, 0, stream>>>(W1, wbt);
    k_wc2<<<4, 256, 0, stream>>>(W2, Wc2);

    // CSR build (XCD-local sub-buckets, nt-hinted streams)
    k_bucket<<<gE, 256, 0, stream>>>(erow, ecol, bcur, bkt, E);
    k_hist<<<NBK, 256, 0, stream>>>(bcur, bkt, cnt, dis, N);
    k_scan1<<<NB, 256, 0, stream>>>(cnt, off, bsum, N);
    k_scan2<<<1, 256, 0, stream>>>(bsum, NB);
    k_scan3<<<gN, 256, 0, stream>>>(off, bsum, N, E);
    k_emit<<<NBK, 256, 0, stream>>>(bcur, bkt, off, scol, N);

    // layer 1: MFMA GEMM (g fast-varying for xb L2 reuse)
    dim3 g1(3, (N + 127) / 128);
    k_gemm1_mfma<<<g1, 256, 0, stream>>>(xb, wbt, dis, ub, sA, wb, N);

    int nw4 = (N + 3) / 4;
    int gP4 = (nw4 * 64 + 255) / 256;
    // sb = bf16( sA - 2*dis^2 * prop-sum(wb) )
    k_prop_b2b<<<gP4, 256, 0, stream>>>(off, scol, wb, sA, dis, sb, N);
    // hb(=wb) = bf16 relu( ub - dis * prop-sum(sb) + b1 )
    k_prop_b2f_relu<<<gP4, 256, 0, stream>>>(off, scol, sb, ub, dis, b1, wb, N);

    // layer 2
    k_gemm2<<<(N + 31) / 32, 256, 0, stream>>>(wb, Wc2, b2, dis, out, s2, w2, N);
    k_prop2_csr<<<gN, 256, 0, stream>>>(off, scol, w2, s2, dis, s2, 1, N);
    k_prop2_csr<<<gN, 256, 0, stream>>>(off, scol, s2, out, dis, out, 0, N);
}

// Round 13
// 682.911 us; speedup vs baseline: 1.1102x; 1.1102x over previous
//
#include <hip/hip_runtime.h>
#include <hip/hip_bf16.h>
#include <stdint.h>

#define NF 165
#define NH 128
#define KP 192          // padded K for MFMA
#define NCOLS 384
#define BSH 8           // rows per bucket = 256
#define BROWS 256
#define BCAP 6144       // whole-bucket capacity for emit LDS buffer
#define NSUB 8          // sub-buckets per bucket (one per XCD)
#define BSUBCAP 768     // per-(bucket,xcd) capacity (mean 512, +11 sigma)
#define CPAD 16         // cursor padding: 16 ints = 64B line

typedef __attribute__((ext_vector_type(8))) short bf16x8;
typedef __attribute__((ext_vector_type(4))) float f32x4;

// ---- bf16 helpers --------------------------------------------------------

__device__ __forceinline__ unsigned short f2bf(float f) {
    unsigned int u = __builtin_bit_cast(unsigned int, f);
    u = (u + 0x7FFFu + ((u >> 16) & 1u)) >> 16;   // RNE
    return (unsigned short)u;
}
__device__ __forceinline__ float bf2f_lo(unsigned int v) {
    return __builtin_bit_cast(float, v << 16);
}
__device__ __forceinline__ float bf2f_hi(unsigned int v) {
    return __builtin_bit_cast(float, v & 0xFFFF0000u);
}

// ---- CSR build ----------------------------------------------------------

// Level-1: append edges to XCD-local sub-buckets. NT loads only here: the
// 25.6MB edge stream is coalesced single-use; keeping it out of L2 preserves
// sub-bucket head lines + cursors -> full-line writebacks.
__global__ __launch_bounds__(256) void k_bucket(
        const int* __restrict__ erow, const int* __restrict__ ecol,
        int* __restrict__ bcur, unsigned int* __restrict__ bkt, int E) {
    int e = blockIdx.x * 256 + threadIdx.x;
    if (e >= E) return;
    int x = blockIdx.x & (NSUB - 1);
    int r = __builtin_nontemporal_load(erow + e);
    int c = __builtin_nontemporal_load(ecol + e);
    int sub = (r >> BSH) * NSUB + x;
    int pos = atomicAdd(&bcur[sub * CPAD], 1);
    if (pos < BSUBCAP)
        bkt[(size_t)sub * BSUBCAP + pos] =
            ((unsigned)(r & (BROWS - 1)) << 18) | (unsigned)c;
}

// Histogram bucket records -> cnt + dis (fused).
__global__ __launch_bounds__(256) void k_hist(
        const int* __restrict__ bcur, const unsigned int* __restrict__ bkt,
        int* __restrict__ cnt, float* __restrict__ dis, int N) {
    __shared__ int h[BROWS];
    int b = blockIdx.x;
    int t = threadIdx.x;
    h[t] = 0;
    __syncthreads();
#pragma unroll
    for (int x = 0; x < NSUB; ++x) {
        int sub = b * NSUB + x;
        int nb = bcur[sub * CPAD];
        if (nb > BSUBCAP) nb = BSUBCAP;
        const unsigned int* src = bkt + (size_t)sub * BSUBCAP;
        for (int i = t; i < nb; i += 256)
            atomicAdd(&h[__builtin_nontemporal_load(src + i) >> 18], 1);
    }
    __syncthreads();
    int base = b << BSH;
    if (base + t < N) {
        int d = h[t];
        cnt[base + t] = d;
        dis[base + t] = (d > 0) ? rsqrtf((float)d) : 0.0f;
    }
}

__global__ __launch_bounds__(256) void k_scan1(
        const int* __restrict__ cnt, int* __restrict__ off,
        int* __restrict__ bsum, int N) {
    __shared__ int sh[256];
    int t = threadIdx.x;
    int base = blockIdx.x * 1024 + t * 4;
    int v0 = (base + 0 < N) ? cnt[base + 0] : 0;
    int v1 = (base + 1 < N) ? cnt[base + 1] : 0;
    int v2 = (base + 2 < N) ? cnt[base + 2] : 0;
    int v3 = (base + 3 < N) ? cnt[base + 3] : 0;
    int tsum = v0 + v1 + v2 + v3;
    sh[t] = tsum;
    __syncthreads();
#pragma unroll
    for (int ofs = 1; ofs < 256; ofs <<= 1) {
        int x = (t >= ofs) ? sh[t - ofs] : 0;
        __syncthreads();
        sh[t] += x;
        __syncthreads();
    }
    int excl = sh[t] - tsum;
    if (t == 255) bsum[blockIdx.x] = sh[t];
    if (base + 0 < N) off[base + 0] = excl;
    excl += v0;
    if (base + 1 < N) off[base + 1] = excl;
    excl += v1;
    if (base + 2 < N) off[base + 2] = excl;
    excl += v2;
    if (base + 3 < N) off[base + 3] = excl;
}

__global__ __launch_bounds__(256) void k_scan2(int* __restrict__ bsum, int NB) {
    __shared__ int sh[256];
    int t = threadIdx.x;
    int v = (t < NB) ? bsum[t] : 0;
    sh[t] = v;
    __syncthreads();
#pragma unroll
    for (int ofs = 1; ofs < 256; ofs <<= 1) {
        int x = (t >= ofs) ? sh[t - ofs] : 0;
        __syncthreads();
        sh[t] += x;
        __syncthreads();
    }
    if (t < NB) bsum[t] = sh[t] - v;
}

__global__ __launch_bounds__(256) void k_scan3(
        int* __restrict__ off, const int* __restrict__ bsum, int N, int E) {
    int i = blockIdx.x * 256 + threadIdx.x;
    if (i >= N) return;
    off[i] = off[i] + bsum[i >> 10];
    if (i == 0) off[N] = E;
}

// Level-2: one block per bucket; place edges at exact CSR slots via LDS,
// then stream out coalesced (normal store: scol is read 4x downstream).
__global__ __launch_bounds__(256) void k_emit(
        const int* __restrict__ bcur, const unsigned int* __restrict__ bkt,
        const int* __restrict__ off, int* __restrict__ scol, int N) {
    __shared__ unsigned colbuf[BCAP];
    __shared__ int rowoff[BROWS + 1];
    __shared__ int cursor[BROWS];

    int b = blockIdx.x;
    int base = b << BSH;
    int nrows = N - base;
    if (nrows > BROWS) nrows = BROWS;
    int t = threadIdx.x;

    for (int i = t; i <= nrows; i += 256) rowoff[i] = off[base + i];
    if (t < BROWS) cursor[t] = 0;
    __syncthreads();

    int regionStart = rowoff[0];
    int total = rowoff[nrows] - regionStart;

#pragma unroll
    for (int x = 0; x < NSUB; ++x) {
        int sub = b * NSUB + x;
        int nb = bcur[sub * CPAD];
        if (nb > BSUBCAP) nb = BSUBCAP;
        const unsigned int* src = bkt + (size_t)sub * BSUBCAP;
        for (int i = t; i < nb; i += 256) {
            unsigned v = __builtin_nontemporal_load(src + i);
            int rl = v >> 18;
            unsigned c = v & 0x3FFFFu;
            int pos = (rowoff[rl] - regionStart) + atomicAdd(&cursor[rl], 1);
            if (pos < BCAP) colbuf[pos] = c;
        }
    }
    __syncthreads();

    for (int i = t; i < total; i += 256) scol[regionStart + i] = (int)colbuf[i];
}

// ---- conversions ---------------------------------------------------------

__global__ __launch_bounds__(256) void k_xb(
        const float* __restrict__ x, unsigned short* __restrict__ xb, int N) {
    int gid = blockIdx.x * 256 + threadIdx.x;
    if (gid >= N * (KP / 8)) return;
    int row = gid / (KP / 8);
    int k0 = (gid % (KP / 8)) * 8;
    unsigned short v[8];
#pragma unroll
    for (int i = 0; i < 8; ++i) {
        int k = k0 + i;
        v[i] = (k < NF) ? f2bf(x[(size_t)row * NF + k]) : (unsigned short)0;
    }
    uint4 pk;
    pk.x = (unsigned)v[0] | ((unsigned)v[1] << 16);
    pk.y = (unsigned)v[2] | ((unsigned)v[3] << 16);
    pk.z = (unsigned)v[4] | ((unsigned)v[5] << 16);
    pk.w = (unsigned)v[6] | ((unsigned)v[7] << 16);
    *(uint4*)(xb + (size_t)row * KP + k0) = pk;
}

__global__ __launch_bounds__(256) void k_wbt(
        const float* __restrict__ W1, unsigned short* __restrict__ wbt) {
    int gid = blockIdx.x * 256 + threadIdx.x;
    if (gid >= NCOLS * (KP / 8)) return;
    int col = gid / (KP / 8);
    int k0 = (gid % (KP / 8)) * 8;
    int cc = col & 127;
    unsigned short v[8];
#pragma unroll
    for (int i = 0; i < 8; ++i) {
        int k = k0 + i;
        float f = 0.0f;
        if (k < NF) {
            if (col < 128)      f = W1[k * 128 + cc] - W1[42240 + k * 128 + cc];
            else if (col < 256) f = W1[21120 + k * 128 + cc];
            else                f = W1[42240 + k * 128 + cc];
        }
        v[i] = f2bf(f);
    }
    uint4 pk;
    pk.x = (unsigned)v[0] | ((unsigned)v[1] << 16);
    pk.y = (unsigned)v[2] | ((unsigned)v[3] << 16);
    pk.z = (unsigned)v[4] | ((unsigned)v[5] << 16);
    pk.w = (unsigned)v[6] | ((unsigned)v[7] << 16);
    *(uint4*)(wbt + (size_t)col * KP + k0) = pk;
}

// Wc2o[128][8], original hidden-index k: c<2: W2[0]-W2[2]; c<4: W2[1]; c<6: W2[2]
__global__ __launch_bounds__(256) void k_wc2o(const float* __restrict__ W2,
                                              float* __restrict__ Wc2o) {
    int gid = blockIdx.x * 256 + threadIdx.x;
    if (gid >= 128 * 8) return;
    int k = gid >> 3;
    int c = gid & 7;
    float v = 0.0f;
    if (c < 2)      v = W2[k * 2 + c] - W2[512 + k * 2 + c];
    else if (c < 4) v = W2[256 + k * 2 + (c - 2)];
    else if (c < 6) v = W2[512 + k * 2 + (c - 4)];
    Wc2o[gid] = v;
}

// ---- GEMM1 via MFMA ------------------------------------------------------
// g==0 -> ub = u (bf16); g==1 -> sA = dis*s (bf16); g==2 -> wb = dis*w (bf16)
__global__ __launch_bounds__(256) void k_gemm1_mfma(
        const unsigned short* __restrict__ xb, const unsigned short* __restrict__ wbt,
        const float* __restrict__ dis,
        unsigned int* __restrict__ ub, unsigned int* __restrict__ sA,
        unsigned int* __restrict__ wb, int N) {
    __shared__ unsigned short As[128][40];
    __shared__ unsigned short Bs[128][40];

    int tid = threadIdx.x;
    int w = tid >> 6;
    int lane = tid & 63;
    int l15 = lane & 15;
    int l16 = lane >> 4;
    int g = blockIdx.x;
    int brow = blockIdx.y * 128;
    int gcol = g * 128;

    int sr = tid >> 1;
    int sk = (tid & 1) * 16;

    f32x4 acc[2][8] = {};

    for (int kc = 0; kc < 6; ++kc) {
        int k0 = kc * 32;
        uint4 va0 = {0, 0, 0, 0}, va1 = {0, 0, 0, 0};
        if (brow + sr < N) {
            const unsigned short* asrc = xb + (size_t)(brow + sr) * KP + k0 + sk;
            va0 = *(const uint4*)asrc;
            va1 = *(const uint4*)(asrc + 8);
        }
        const unsigned short* bsrc = wbt + (size_t)(gcol + sr) * KP + k0 + sk;
        uint4 vb0 = *(const uint4*)bsrc;
        uint4 vb1 = *(const uint4*)(bsrc + 8);
        __syncthreads();
        *(uint4*)&As[sr][sk] = va0;
        *(uint4*)&As[sr][sk + 8] = va1;
        *(uint4*)&Bs[sr][sk] = vb0;
        *(uint4*)&Bs[sr][sk + 8] = vb1;
        __syncthreads();

        bf16x8 a[2], b[8];
#pragma unroll
        for (int m = 0; m < 2; ++m)
            a[m] = *(const bf16x8*)&As[w * 32 + m * 16 + l15][l16 * 8];
#pragma unroll
        for (int n = 0; n < 8; ++n)
            b[n] = *(const bf16x8*)&Bs[n * 16 + l15][l16 * 8];
#pragma unroll
        for (int m = 0; m < 2; ++m)
#pragma unroll
            for (int n = 0; n < 8; ++n)
                acc[m][n] = __builtin_amdgcn_mfma_f32_16x16x32_bf16(
                    a[m], b[n], acc[m][n], 0, 0, 0);
    }

    unsigned int* dst = (g == 0) ? ub : (g == 1) ? sA : wb;
#pragma unroll
    for (int m = 0; m < 2; ++m) {
#pragma unroll
        for (int reg = 0; reg < 4; ++reg) {
            int row = brow + w * 32 + m * 16 + l16 * 4 + reg;
            if (row >= N) continue;
            float sc = (g == 0) ? 1.0f : dis[row];
#pragma unroll
            for (int n = 0; n < 4; ++n) {
                int c = n * 16 + l15;
                float lo = sc * acc[m][n][reg];
                float hi = sc * acc[m][n + 4][reg];
                dst[(size_t)row * 64 + c] =
                    (unsigned)f2bf(lo) | ((unsigned)f2bf(hi) << 16);
            }
        }
    }
}

// ---- 128-wide props: 4 rows/wave, 16 lanes/row, uint4 gathers, unroll-2 ---

// sb[r] = bf16( sA[r] - 2*dis[r]^2 * sum_e wb[col] )
__global__ __launch_bounds__(256) void k_prop_b2b(
        const int* __restrict__ off, const int* __restrict__ scol,
        const unsigned int* __restrict__ srcb, const unsigned int* __restrict__ addb,
        const float* __restrict__ dis, unsigned int* __restrict__ dstb, int N) {
    int wid = (blockIdx.x * 256 + threadIdx.x) >> 6;
    int lane = threadIdx.x & 63;
    int g = lane >> 4, q = lane & 15;
    int r = wid * 4 + g;
    if (r >= N) return;
    int e = off[r], end = off[r + 1];
    const uint4* src4 = (const uint4*)srcb;
    float a[8] = {}, b[8] = {};
    for (; e + 2 <= end; e += 2) {
        int c0 = scol[e], c1 = scol[e + 1];
        uint4 v0 = src4[(size_t)c0 * 16 + q];
        uint4 v1 = src4[(size_t)c1 * 16 + q];
        unsigned vv0[4] = {v0.x, v0.y, v0.z, v0.w};
        unsigned vv1[4] = {v1.x, v1.y, v1.z, v1.w};
#pragma unroll
        for (int j = 0; j < 4; ++j) {
            a[2 * j] += bf2f_lo(vv0[j]); a[2 * j + 1] += bf2f_hi(vv0[j]);
            b[2 * j] += bf2f_lo(vv1[j]); b[2 * j + 1] += bf2f_hi(vv1[j]);
        }
    }
    if (e < end) {
        int c0 = scol[e];
        uint4 v0 = src4[(size_t)c0 * 16 + q];
        unsigned vv0[4] = {v0.x, v0.y, v0.z, v0.w};
#pragma unroll
        for (int j = 0; j < 4; ++j) {
            a[2 * j] += bf2f_lo(vv0[j]); a[2 * j + 1] += bf2f_hi(vv0[j]);
        }
    }
    float d = dis[r];
    float m2 = -2.0f * d * d;
    uint4 ad = ((const uint4*)addb)[(size_t)r * 16 + q];
    unsigned adp[4] = {ad.x, ad.y, ad.z, ad.w};
    uint4 o;
    unsigned* op = (unsigned*)&o;
#pragma unroll
    for (int j = 0; j < 4; ++j) {
        float lo = bf2f_lo(adp[j]) + m2 * (a[2 * j] + b[2 * j]);
        float hi = bf2f_hi(adp[j]) + m2 * (a[2 * j + 1] + b[2 * j + 1]);
        op[j] = (unsigned)f2bf(lo) | ((unsigned)f2bf(hi) << 16);
    }
    ((uint4*)dstb)[(size_t)r * 16 + q] = o;
}

// Fused: h = relu(ub - dis*prop(sb) + b1) kept in registers, immediately
// contracted with Wc2o -> out(+b2), s2=dis*., w2=dis*.  (h never hits memory)
__global__ __launch_bounds__(256) void k_prop_b2f_gemm2(
        const int* __restrict__ off, const int* __restrict__ scol,
        const unsigned int* __restrict__ srcb, const unsigned int* __restrict__ addb,
        const float* __restrict__ dis, const float* __restrict__ b1,
        const float* __restrict__ Wc2o, const float* __restrict__ b2,
        float* __restrict__ out, float* __restrict__ s2, float* __restrict__ w2,
        int N) {
    __shared__ float Ws[128 * 8];
    int tid = threadIdx.x;
    for (int idx = tid; idx < 128 * 8; idx += 256) Ws[idx] = Wc2o[idx];
    __syncthreads();

    int wid = (blockIdx.x * 256 + tid) >> 6;
    int lane = tid & 63;
    int g = lane >> 4, q = lane & 15;
    int r = wid * 4 + g;
    if (r >= N) return;
    int e = off[r], end = off[r + 1];
    const uint4* src4 = (const uint4*)srcb;
    float a[8] = {}, b[8] = {};
    for (; e + 2 <= end; e += 2) {
        int c0 = scol[e], c1 = scol[e + 1];
        uint4 v0 = src4[(size_t)c0 * 16 + q];
        uint4 v1 = src4[(size_t)c1 * 16 + q];
        unsigned vv0[4] = {v0.x, v0.y, v0.z, v0.w};
        unsigned vv1[4] = {v1.x, v1.y, v1.z, v1.w};
#pragma unroll
        for (int j = 0; j < 4; ++j) {
            a[2 * j] += bf2f_lo(vv0[j]); a[2 * j + 1] += bf2f_hi(vv0[j]);
            b[2 * j] += bf2f_lo(vv1[j]); b[2 * j + 1] += bf2f_hi(vv1[j]);
        }
    }
    if (e < end) {
        int c0 = scol[e];
        uint4 v0 = src4[(size_t)c0 * 16 + q];
        unsigned vv0[4] = {v0.x, v0.y, v0.z, v0.w};
#pragma unroll
        for (int j = 0; j < 4; ++j) {
            a[2 * j] += bf2f_lo(vv0[j]); a[2 * j + 1] += bf2f_hi(vv0[j]);
        }
    }
    float m1 = -dis[r];
    uint4 ad = ((const uint4*)addb)[(size_t)r * 16 + q];
    unsigned adp[4] = {ad.x, ad.y, ad.z, ad.w};
    float acc[6] = {};
#pragma unroll
    for (int j = 0; j < 4; ++j) {
        int c = q * 4 + j;
        float lo = fmaxf(bf2f_lo(adp[j]) + m1 * (a[2 * j] + b[2 * j]) + b1[c], 0.0f);
        float hi = fmaxf(bf2f_hi(adp[j]) + m1 * (a[2 * j + 1] + b[2 * j + 1]) + b1[c + 64], 0.0f);
        const float* w0 = &Ws[c * 8];
        const float* w1 = &Ws[(c + 64) * 8];
#pragma unroll
        for (int t = 0; t < 6; ++t)
            acc[t] += lo * w0[t] + hi * w1[t];
    }
    // reduce across the 16 lanes of this row group (masks < 16 stay in group)
#pragma unroll
    for (int ofs = 8; ofs; ofs >>= 1) {
#pragma unroll
        for (int t = 0; t < 6; ++t)
            acc[t] += __shfl_xor(acc[t], ofs);
    }
    if (q == 0) {
        float d = dis[r];
        out[(size_t)r * 2 + 0] = acc[0] + b2[0];
        out[(size_t)r * 2 + 1] = acc[1] + b2[1];
        s2[(size_t)r * 2 + 0] = d * acc[2];
        s2[(size_t)r * 2 + 1] = d * acc[3];
        w2[(size_t)r * 2 + 0] = d * acc[4];
        w2[(size_t)r * 2 + 1] = d * acc[5];
    }
}

// CSR prop, 2-wide: dst[r] = add[r] + m * sum src[col], m = sq ? -2*dis^2 : -dis.
__global__ __launch_bounds__(256) void k_prop2_csr(
        const int* __restrict__ off, const int* __restrict__ scol,
        const float* __restrict__ src, const float* __restrict__ add,
        const float* __restrict__ dis, float* __restrict__ dst,
        int sq, int N) {
    int r = blockIdx.x * 256 + threadIdx.x;
    if (r >= N) return;
    int e0 = off[r], e1 = off[r + 1];
    float a0 = 0.0f, a1 = 0.0f;
    for (int e = e0; e < e1; ++e) {
        int c = scol[e];
        float2 v = *(const float2*)(src + (size_t)c * 2);
        a0 += v.x;
        a1 += v.y;
    }
    float d = dis[r];
    float m = sq ? (-2.0f * d * d) : (-d);
    float2 ad = *(const float2*)(add + (size_t)r * 2);
    float2 o = {ad.x + m * a0, ad.y + m * a1};
    *(float2*)(dst + (size_t)r * 2) = o;
}

extern "C" void kernel_launch(void* const* d_in, const int* in_sizes, int n_in,
                              void* d_out, int out_size, void* d_ws, size_t ws_size,
                              hipStream_t stream) {
    const float* x   = (const float*)d_in[0];
    const int* eidx  = (const int*)d_in[1];
    const float* W1  = (const float*)d_in[2];
    const float* b1  = (const float*)d_in[3];
    const float* W2  = (const float*)d_in[4];
    const float* b2  = (const float*)d_in[5];
    float* out       = (float*)d_out;

    int N = in_sizes[0] / NF;
    int E = in_sizes[1] / 2;
    const int* erow = eidx;
    const int* ecol = eidx + E;
    int NBK = (N + BROWS - 1) >> BSH;

    char* p = (char*)d_ws;
    auto alloc = [&](size_t bytes) {
        char* q = p;
        p += (bytes + 255) & ~(size_t)255;
        return q;
    };
    unsigned int* ub = (unsigned int*)alloc((size_t)N * 64 * 4);
    unsigned int* sA = (unsigned int*)alloc((size_t)N * 64 * 4);
    unsigned int* wb = (unsigned int*)alloc((size_t)N * 64 * 4);
    unsigned int* sb = (unsigned int*)alloc((size_t)N * 64 * 4);
    unsigned short* xb  = (unsigned short*)alloc((size_t)N * KP * 2);
    unsigned short* wbt = (unsigned short*)alloc((size_t)NCOLS * KP * 2);
    float* dis  = (float*)alloc((size_t)N * 4);
    int* cnt    = (int*)alloc((size_t)N * 4);
    int* off    = (int*)alloc((size_t)(N + 1) * 4);
    int* bsum   = (int*)alloc((size_t)256 * 4);
    int* bcur   = (int*)alloc((size_t)NBK * NSUB * CPAD * 4);
    unsigned int* bkt = (unsigned int*)alloc((size_t)NBK * NSUB * BSUBCAP * 4);
    int* scol   = (int*)alloc((size_t)E * 4);
    float* Wc2o = (float*)alloc((size_t)128 * 8 * 4);
    float* s2   = (float*)alloc((size_t)N * 2 * 4);
    float* w2   = (float*)alloc((size_t)N * 2 * 4);

    hipMemsetAsync(bcur, 0, (size_t)NBK * NSUB * CPAD * 4, stream);

    int gE = (E + 255) / 256;
    int gN = (N + 255) / 256;
    int NB = (N + 1023) / 1024;

    // conversions
    k_xb<<<(N * (KP / 8) + 255) / 256, 256, 0, stream>>>(x, xb, N);
    k_wbt<<<(NCOLS * (KP / 8) + 255) / 256, 256, 0, stream>>>(W1, wbt);
    k_wc2o<<<4, 256, 0, stream>>>(W2, Wc2o);

    // CSR build (XCD-local sub-buckets)
    k_bucket<<<gE, 256, 0, stream>>>(erow, ecol, bcur, bkt, E);
    k_hist<<<NBK, 256, 0, stream>>>(bcur, bkt, cnt, dis, N);
    k_scan1<<<NB, 256, 0, stream>>>(cnt, off, bsum, N);
    k_scan2<<<1, 256, 0, stream>>>(bsum, NB);
    k_scan3<<<gN, 256, 0, stream>>>(off, bsum, N, E);
    k_emit<<<NBK, 256, 0, stream>>>(bcur, bkt, off, scol, N);

    // layer 1: MFMA GEMM (g fast-varying for xb L2 reuse)
    dim3 g1(3, (N + 127) / 128);
    k_gemm1_mfma<<<g1, 256, 0, stream>>>(xb, wbt, dis, ub, sA, wb, N);

    int nw4 = (N + 3) / 4;
    int gP4 = (nw4 * 64 + 255) / 256;
    // sb = bf16( sA - 2*dis^2 * prop-sum(wb) )
    k_prop_b2b<<<gP4, 256, 0, stream>>>(off, scol, wb, sA, dis, sb, N);
    // fused: h = relu(ub - dis*prop-sum(sb) + b1); out/s2/w2 = h @ Wc2o
    k_prop_b2f_gemm2<<<gP4, 256, 0, stream>>>(off, scol, sb, ub, dis, b1,
                                              Wc2o, b2, out, s2, w2, N);

    // layer 2 props (2-wide)
    k_prop2_csr<<<gN, 256, 0, stream>>>(off, scol, w2, s2, dis, s2, 1, N);
    k_prop2_csr<<<gN, 256, 0, stream>>>(off, scol, s2, out, dis, out, 0, N);
}

// Round 14
// 662.854 us; speedup vs baseline: 1.1438x; 1.0303x over previous
//
#include <hip/hip_runtime.h>
#include <hip/hip_bf16.h>
#include <stdint.h>

#define NF 165
#define NH 128
#define KP 192          // padded K for MFMA
#define NCOLS 384
#define BSH 8           // rows per bucket = 256
#define BROWS 256
#define BCAP 6144       // whole-bucket capacity for emit LDS buffer
#define NSUB 8          // sub-buckets per bucket (one per XCD)
#define BSUBCAP 768     // per-(bucket,xcd) capacity (mean 512, +11 sigma)
#define CPAD 16         // cursor padding: 16 ints = 64B line

typedef __attribute__((ext_vector_type(8))) short bf16x8;
typedef __attribute__((ext_vector_type(4))) float f32x4;

// ---- bf16 helpers --------------------------------------------------------

__device__ __forceinline__ unsigned short f2bf(float f) {
    unsigned int u = __builtin_bit_cast(unsigned int, f);
    u = (u + 0x7FFFu + ((u >> 16) & 1u)) >> 16;   // RNE
    return (unsigned short)u;
}
__device__ __forceinline__ float bf2f_lo(unsigned int v) {
    return __builtin_bit_cast(float, v << 16);
}
__device__ __forceinline__ float bf2f_hi(unsigned int v) {
    return __builtin_bit_cast(float, v & 0xFFFF0000u);
}

// ---- CSR build ----------------------------------------------------------

// Level-1: append edges to XCD-local sub-buckets. NT loads only here: the
// 25.6MB edge stream is coalesced single-use; keeping it out of L2 preserves
// sub-bucket head lines + cursors -> full-line writebacks.
__global__ __launch_bounds__(256) void k_bucket(
        const int* __restrict__ erow, const int* __restrict__ ecol,
        int* __restrict__ bcur, unsigned int* __restrict__ bkt, int E) {
    int e = blockIdx.x * 256 + threadIdx.x;
    if (e >= E) return;
    int x = blockIdx.x & (NSUB - 1);
    int r = __builtin_nontemporal_load(erow + e);
    int c = __builtin_nontemporal_load(ecol + e);
    int sub = (r >> BSH) * NSUB + x;
    int pos = atomicAdd(&bcur[sub * CPAD], 1);
    if (pos < BSUBCAP)
        bkt[(size_t)sub * BSUBCAP + pos] =
            ((unsigned)(r & (BROWS - 1)) << 18) | (unsigned)c;
}

// Histogram bucket records -> cnt + dis (fused).
__global__ __launch_bounds__(256) void k_hist(
        const int* __restrict__ bcur, const unsigned int* __restrict__ bkt,
        int* __restrict__ cnt, float* __restrict__ dis, int N) {
    __shared__ int h[BROWS];
    int b = blockIdx.x;
    int t = threadIdx.x;
    h[t] = 0;
    __syncthreads();
#pragma unroll
    for (int x = 0; x < NSUB; ++x) {
        int sub = b * NSUB + x;
        int nb = bcur[sub * CPAD];
        if (nb > BSUBCAP) nb = BSUBCAP;
        const unsigned int* src = bkt + (size_t)sub * BSUBCAP;
        for (int i = t; i < nb; i += 256)
            atomicAdd(&h[__builtin_nontemporal_load(src + i) >> 18], 1);
    }
    __syncthreads();
    int base = b << BSH;
    if (base + t < N) {
        int d = h[t];
        cnt[base + t] = d;
        dis[base + t] = (d > 0) ? rsqrtf((float)d) : 0.0f;
    }
}

__global__ __launch_bounds__(256) void k_scan1(
        const int* __restrict__ cnt, int* __restrict__ off,
        int* __restrict__ bsum, int N) {
    __shared__ int sh[256];
    int t = threadIdx.x;
    int base = blockIdx.x * 1024 + t * 4;
    int v0 = (base + 0 < N) ? cnt[base + 0] : 0;
    int v1 = (base + 1 < N) ? cnt[base + 1] : 0;
    int v2 = (base + 2 < N) ? cnt[base + 2] : 0;
    int v3 = (base + 3 < N) ? cnt[base + 3] : 0;
    int tsum = v0 + v1 + v2 + v3;
    sh[t] = tsum;
    __syncthreads();
#pragma unroll
    for (int ofs = 1; ofs < 256; ofs <<= 1) {
        int x = (t >= ofs) ? sh[t - ofs] : 0;
        __syncthreads();
        sh[t] += x;
        __syncthreads();
    }
    int excl = sh[t] - tsum;
    if (t == 255) bsum[blockIdx.x] = sh[t];
    if (base + 0 < N) off[base + 0] = excl;
    excl += v0;
    if (base + 1 < N) off[base + 1] = excl;
    excl += v1;
    if (base + 2 < N) off[base + 2] = excl;
    excl += v2;
    if (base + 3 < N) off[base + 3] = excl;
}

__global__ __launch_bounds__(256) void k_scan2(int* __restrict__ bsum, int NB) {
    __shared__ int sh[256];
    int t = threadIdx.x;
    int v = (t < NB) ? bsum[t] : 0;
    sh[t] = v;
    __syncthreads();
#pragma unroll
    for (int ofs = 1; ofs < 256; ofs <<= 1) {
        int x = (t >= ofs) ? sh[t - ofs] : 0;
        __syncthreads();
        sh[t] += x;
        __syncthreads();
    }
    if (t < NB) bsum[t] = sh[t] - v;
}

__global__ __launch_bounds__(256) void k_scan3(
        int* __restrict__ off, const int* __restrict__ bsum, int N, int E) {
    int i = blockIdx.x * 256 + threadIdx.x;
    if (i >= N) return;
    off[i] = off[i] + bsum[i >> 10];
    if (i == 0) off[N] = E;
}

// Level-2: one block per bucket; place edges at exact CSR slots via LDS,
// then stream out coalesced.
__global__ __launch_bounds__(256) void k_emit(
        const int* __restrict__ bcur, const unsigned int* __restrict__ bkt,
        const int* __restrict__ off, int* __restrict__ scol, int N) {
    __shared__ unsigned colbuf[BCAP];
    __shared__ int rowoff[BROWS + 1];
    __shared__ int cursor[BROWS];

    int b = blockIdx.x;
    int base = b << BSH;
    int nrows = N - base;
    if (nrows > BROWS) nrows = BROWS;
    int t = threadIdx.x;

    for (int i = t; i <= nrows; i += 256) rowoff[i] = off[base + i];
    if (t < BROWS) cursor[t] = 0;
    __syncthreads();

    int regionStart = rowoff[0];
    int total = rowoff[nrows] - regionStart;

#pragma unroll
    for (int x = 0; x < NSUB; ++x) {
        int sub = b * NSUB + x;
        int nb = bcur[sub * CPAD];
        if (nb > BSUBCAP) nb = BSUBCAP;
        const unsigned int* src = bkt + (size_t)sub * BSUBCAP;
        for (int i = t; i < nb; i += 256) {
            unsigned v = __builtin_nontemporal_load(src + i);
            int rl = v >> 18;
            unsigned c = v & 0x3FFFFu;
            int pos = (rowoff[rl] - regionStart) + atomicAdd(&cursor[rl], 1);
            if (pos < BCAP) colbuf[pos] = c;
        }
    }
    __syncthreads();

    for (int i = t; i < total; i += 256) scol[regionStart + i] = (int)colbuf[i];
}

// ---- conversions ---------------------------------------------------------

__global__ __launch_bounds__(256) void k_xb(
        const float* __restrict__ x, unsigned short* __restrict__ xb, int N) {
    int gid = blockIdx.x * 256 + threadIdx.x;
    if (gid >= N * (KP / 8)) return;
    int row = gid / (KP / 8);
    int k0 = (gid % (KP / 8)) * 8;
    unsigned short v[8];
#pragma unroll
    for (int i = 0; i < 8; ++i) {
        int k = k0 + i;
        v[i] = (k < NF) ? f2bf(x[(size_t)row * NF + k]) : (unsigned short)0;
    }
    uint4 pk;
    pk.x = (unsigned)v[0] | ((unsigned)v[1] << 16);
    pk.y = (unsigned)v[2] | ((unsigned)v[3] << 16);
    pk.z = (unsigned)v[4] | ((unsigned)v[5] << 16);
    pk.w = (unsigned)v[6] | ((unsigned)v[7] << 16);
    *(uint4*)(xb + (size_t)row * KP + k0) = pk;
}

__global__ __launch_bounds__(256) void k_wbt(
        const float* __restrict__ W1, unsigned short* __restrict__ wbt) {
    int gid = blockIdx.x * 256 + threadIdx.x;
    if (gid >= NCOLS * (KP / 8)) return;
    int col = gid / (KP / 8);
    int k0 = (gid % (KP / 8)) * 8;
    int cc = col & 127;
    unsigned short v[8];
#pragma unroll
    for (int i = 0; i < 8; ++i) {
        int k = k0 + i;
        float f = 0.0f;
        if (k < NF) {
            if (col < 128)      f = W1[k * 128 + cc] - W1[42240 + k * 128 + cc];
            else if (col < 256) f = W1[21120 + k * 128 + cc];
            else                f = W1[42240 + k * 128 + cc];
        }
        v[i] = f2bf(f);
    }
    uint4 pk;
    pk.x = (unsigned)v[0] | ((unsigned)v[1] << 16);
    pk.y = (unsigned)v[2] | ((unsigned)v[3] << 16);
    pk.z = (unsigned)v[4] | ((unsigned)v[5] << 16);
    pk.w = (unsigned)v[6] | ((unsigned)v[7] << 16);
    *(uint4*)(wbt + (size_t)col * KP + k0) = pk;
}

// Wc2t[8][128] TRANSPOSED: row t (output col), col k (hidden).
// t<2: W2[0]-W2[2]; t<4: W2[1]; t<6: W2[2]; t>=6: 0.
__global__ __launch_bounds__(256) void k_wc2t(const float* __restrict__ W2,
                                              float* __restrict__ Wc2t) {
    int gid = blockIdx.x * 256 + threadIdx.x;
    if (gid >= 8 * 128) return;
    int t = gid >> 7;
    int k = gid & 127;
    float v = 0.0f;
    if (t < 2)      v = W2[k * 2 + t] - W2[512 + k * 2 + t];
    else if (t < 4) v = W2[256 + k * 2 + (t - 2)];
    else if (t < 6) v = W2[512 + k * 2 + (t - 4)];
    Wc2t[gid] = v;
}

// ---- GEMM1 via MFMA ------------------------------------------------------
// g==0 -> ub = u (bf16); g==1 -> sA = dis*s (bf16); g==2 -> wb = dis*w (bf16)
__global__ __launch_bounds__(256) void k_gemm1_mfma(
        const unsigned short* __restrict__ xb, const unsigned short* __restrict__ wbt,
        const float* __restrict__ dis,
        unsigned int* __restrict__ ub, unsigned int* __restrict__ sA,
        unsigned int* __restrict__ wb, int N) {
    __shared__ unsigned short As[128][40];
    __shared__ unsigned short Bs[128][40];

    int tid = threadIdx.x;
    int w = tid >> 6;
    int lane = tid & 63;
    int l15 = lane & 15;
    int l16 = lane >> 4;
    int g = blockIdx.x;
    int brow = blockIdx.y * 128;
    int gcol = g * 128;

    int sr = tid >> 1;
    int sk = (tid & 1) * 16;

    f32x4 acc[2][8] = {};

    for (int kc = 0; kc < 6; ++kc) {
        int k0 = kc * 32;
        uint4 va0 = {0, 0, 0, 0}, va1 = {0, 0, 0, 0};
        if (brow + sr < N) {
            const unsigned short* asrc = xb + (size_t)(brow + sr) * KP + k0 + sk;
            va0 = *(const uint4*)asrc;
            va1 = *(const uint4*)(asrc + 8);
        }
        const unsigned short* bsrc = wbt + (size_t)(gcol + sr) * KP + k0 + sk;
        uint4 vb0 = *(const uint4*)bsrc;
        uint4 vb1 = *(const uint4*)(bsrc + 8);
        __syncthreads();
        *(uint4*)&As[sr][sk] = va0;
        *(uint4*)&As[sr][sk + 8] = va1;
        *(uint4*)&Bs[sr][sk] = vb0;
        *(uint4*)&Bs[sr][sk + 8] = vb1;
        __syncthreads();

        bf16x8 a[2], b[8];
#pragma unroll
        for (int m = 0; m < 2; ++m)
            a[m] = *(const bf16x8*)&As[w * 32 + m * 16 + l15][l16 * 8];
#pragma unroll
        for (int n = 0; n < 8; ++n)
            b[n] = *(const bf16x8*)&Bs[n * 16 + l15][l16 * 8];
#pragma unroll
        for (int m = 0; m < 2; ++m)
#pragma unroll
            for (int n = 0; n < 8; ++n)
                acc[m][n] = __builtin_amdgcn_mfma_f32_16x16x32_bf16(
                    a[m], b[n], acc[m][n], 0, 0, 0);
    }

    unsigned int* dst = (g == 0) ? ub : (g == 1) ? sA : wb;
#pragma unroll
    for (int m = 0; m < 2; ++m) {
#pragma unroll
        for (int reg = 0; reg < 4; ++reg) {
            int row = brow + w * 32 + m * 16 + l16 * 4 + reg;
            if (row >= N) continue;
            float sc = (g == 0) ? 1.0f : dis[row];
#pragma unroll
            for (int n = 0; n < 4; ++n) {
                int c = n * 16 + l15;
                float lo = sc * acc[m][n][reg];
                float hi = sc * acc[m][n + 4][reg];
                dst[(size_t)row * 64 + c] =
                    (unsigned)f2bf(lo) | ((unsigned)f2bf(hi) << 16);
            }
        }
    }
}

// ---- 128-wide props: 4 rows/wave, 16 lanes/row, uint4 gathers, unroll-2 ---

// sb[r] = bf16( sA[r] - 2*dis[r]^2 * sum_e wb[col] )
__global__ __launch_bounds__(256) void k_prop_b2b(
        const int* __restrict__ off, const int* __restrict__ scol,
        const unsigned int* __restrict__ srcb, const unsigned int* __restrict__ addb,
        const float* __restrict__ dis, unsigned int* __restrict__ dstb, int N) {
    int wid = (blockIdx.x * 256 + threadIdx.x) >> 6;
    int lane = threadIdx.x & 63;
    int g = lane >> 4, q = lane & 15;
    int r = wid * 4 + g;
    if (r >= N) return;
    int e = off[r], end = off[r + 1];
    const uint4* src4 = (const uint4*)srcb;
    float a[8] = {}, b[8] = {};
    for (; e + 2 <= end; e += 2) {
        int c0 = scol[e], c1 = scol[e + 1];
        uint4 v0 = src4[(size_t)c0 * 16 + q];
        uint4 v1 = src4[(size_t)c1 * 16 + q];
        unsigned vv0[4] = {v0.x, v0.y, v0.z, v0.w};
        unsigned vv1[4] = {v1.x, v1.y, v1.z, v1.w};
#pragma unroll
        for (int j = 0; j < 4; ++j) {
            a[2 * j] += bf2f_lo(vv0[j]); a[2 * j + 1] += bf2f_hi(vv0[j]);
            b[2 * j] += bf2f_lo(vv1[j]); b[2 * j + 1] += bf2f_hi(vv1[j]);
        }
    }
    if (e < end) {
        int c0 = scol[e];
        uint4 v0 = src4[(size_t)c0 * 16 + q];
        unsigned vv0[4] = {v0.x, v0.y, v0.z, v0.w};
#pragma unroll
        for (int j = 0; j < 4; ++j) {
            a[2 * j] += bf2f_lo(vv0[j]); a[2 * j + 1] += bf2f_hi(vv0[j]);
        }
    }
    float d = dis[r];
    float m2 = -2.0f * d * d;
    uint4 ad = ((const uint4*)addb)[(size_t)r * 16 + q];
    unsigned adp[4] = {ad.x, ad.y, ad.z, ad.w};
    uint4 o;
    unsigned* op = (unsigned*)&o;
#pragma unroll
    for (int j = 0; j < 4; ++j) {
        float lo = bf2f_lo(adp[j]) + m2 * (a[2 * j] + b[2 * j]);
        float hi = bf2f_hi(adp[j]) + m2 * (a[2 * j + 1] + b[2 * j + 1]);
        op[j] = (unsigned)f2bf(lo) | ((unsigned)f2bf(hi) << 16);
    }
    ((uint4*)dstb)[(size_t)r * 16 + q] = o;
}

// Fused: h = relu(ub - dis*prop(sb) + b1) in registers, contracted with
// Wc2t (transposed LDS: Ws[t*128+c], bank = c%32 -> 2-way only, free).
__global__ __launch_bounds__(256) void k_prop_b2f_gemm2(
        const int* __restrict__ off, const int* __restrict__ scol,
        const unsigned int* __restrict__ srcb, const unsigned int* __restrict__ addb,
        const float* __restrict__ dis, const float* __restrict__ b1,
        const float* __restrict__ Wc2t, const float* __restrict__ b2,
        float* __restrict__ out, float* __restrict__ s2, float* __restrict__ w2,
        int N) {
    __shared__ float Ws[8 * 128];
    int tid = threadIdx.x;
    for (int idx = tid; idx < 8 * 128; idx += 256) Ws[idx] = Wc2t[idx];
    __syncthreads();

    int wid = (blockIdx.x * 256 + tid) >> 6;
    int lane = tid & 63;
    int g = lane >> 4, q = lane & 15;
    int r = wid * 4 + g;
    if (r >= N) return;

    // preload per-lane bias (8 values: cols q*4+j and q*4+j+64)
    float blo[4], bhi[4];
#pragma unroll
    for (int j = 0; j < 4; ++j) {
        blo[j] = b1[q * 4 + j];
        bhi[j] = b1[q * 4 + j + 64];
    }

    int e = off[r], end = off[r + 1];
    const uint4* src4 = (const uint4*)srcb;
    float a[8] = {}, b[8] = {};
    for (; e + 2 <= end; e += 2) {
        int c0 = scol[e], c1 = scol[e + 1];
        uint4 v0 = src4[(size_t)c0 * 16 + q];
        uint4 v1 = src4[(size_t)c1 * 16 + q];
        unsigned vv0[4] = {v0.x, v0.y, v0.z, v0.w};
        unsigned vv1[4] = {v1.x, v1.y, v1.z, v1.w};
#pragma unroll
        for (int j = 0; j < 4; ++j) {
            a[2 * j] += bf2f_lo(vv0[j]); a[2 * j + 1] += bf2f_hi(vv0[j]);
            b[2 * j] += bf2f_lo(vv1[j]); b[2 * j + 1] += bf2f_hi(vv1[j]);
        }
    }
    if (e < end) {
        int c0 = scol[e];
        uint4 v0 = src4[(size_t)c0 * 16 + q];
        unsigned vv0[4] = {v0.x, v0.y, v0.z, v0.w};
#pragma unroll
        for (int j = 0; j < 4; ++j) {
            a[2 * j] += bf2f_lo(vv0[j]); a[2 * j + 1] += bf2f_hi(vv0[j]);
        }
    }
    float m1 = -dis[r];
    uint4 ad = ((const uint4*)addb)[(size_t)r * 16 + q];
    unsigned adp[4] = {ad.x, ad.y, ad.z, ad.w};
    float acc[6] = {};
#pragma unroll
    for (int j = 0; j < 4; ++j) {
        int c = q * 4 + j;
        float lo = fmaxf(bf2f_lo(adp[j]) + m1 * (a[2 * j] + b[2 * j]) + blo[j], 0.0f);
        float hi = fmaxf(bf2f_hi(adp[j]) + m1 * (a[2 * j + 1] + b[2 * j + 1]) + bhi[j], 0.0f);
#pragma unroll
        for (int t = 0; t < 6; ++t)
            acc[t] += lo * Ws[t * 128 + c] + hi * Ws[t * 128 + c + 64];
    }
    // reduce across the 16 lanes of this row group
#pragma unroll
    for (int ofs = 8; ofs; ofs >>= 1) {
#pragma unroll
        for (int t = 0; t < 6; ++t)
            acc[t] += __shfl_xor(acc[t], ofs);
    }
    if (q == 0) {
        float d = dis[r];
        out[(size_t)r * 2 + 0] = acc[0] + b2[0];
        out[(size_t)r * 2 + 1] = acc[1] + b2[1];
        s2[(size_t)r * 2 + 0] = d * acc[2];
        s2[(size_t)r * 2 + 1] = d * acc[3];
        w2[(size_t)r * 2 + 0] = d * acc[4];
        w2[(size_t)r * 2 + 1] = d * acc[5];
    }
}

// CSR prop, 2-wide: dst[r] = add[r] + m * sum src[col], m = sq ? -2*dis^2 : -dis.
__global__ __launch_bounds__(256) void k_prop2_csr(
        const int* __restrict__ off, const int* __restrict__ scol,
        const float* __restrict__ src, const float* __restrict__ add,
        const float* __restrict__ dis, float* __restrict__ dst,
        int sq, int N) {
    int r = blockIdx.x * 256 + threadIdx.x;
    if (r >= N) return;
    int e0 = off[r], e1 = off[r + 1];
    float a0 = 0.0f, a1 = 0.0f;
    for (int e = e0; e < e1; ++e) {
        int c = scol[e];
        float2 v = *(const float2*)(src + (size_t)c * 2);
        a0 += v.x;
        a1 += v.y;
    }
    float d = dis[r];
    float m = sq ? (-2.0f * d * d) : (-d);
    float2 ad = *(const float2*)(add + (size_t)r * 2);
    float2 o = {ad.x + m * a0, ad.y + m * a1};
    *(float2*)(dst + (size_t)r * 2) = o;
}

extern "C" void kernel_launch(void* const* d_in, const int* in_sizes, int n_in,
                              void* d_out, int out_size, void* d_ws, size_t ws_size,
                              hipStream_t stream) {
    const float* x   = (const float*)d_in[0];
    const int* eidx  = (const int*)d_in[1];
    const float* W1  = (const float*)d_in[2];
    const float* b1  = (const float*)d_in[3];
    const float* W2  = (const float*)d_in[4];
    const float* b2  = (const float*)d_in[5];
    float* out       = (float*)d_out;

    int N = in_sizes[0] / NF;
    int E = in_sizes[1] / 2;
    const int* erow = eidx;
    const int* ecol = eidx + E;
    int NBK = (N + BROWS - 1) >> BSH;

    char* p = (char*)d_ws;
    auto alloc = [&](size_t bytes) {
        char* q = p;
        p += (bytes + 255) & ~(size_t)255;
        return q;
    };
    unsigned int* ub = (unsigned int*)alloc((size_t)N * 64 * 4);
    unsigned int* sA = (unsigned int*)alloc((size_t)N * 64 * 4);
    unsigned int* wb = (unsigned int*)alloc((size_t)N * 64 * 4);
    unsigned int* sb = (unsigned int*)alloc((size_t)N * 64 * 4);
    unsigned short* xb  = (unsigned short*)alloc((size_t)N * KP * 2);
    unsigned short* wbt = (unsigned short*)alloc((size_t)NCOLS * KP * 2);
    float* dis  = (float*)alloc((size_t)N * 4);
    int* cnt    = (int*)alloc((size_t)N * 4);
    int* off    = (int*)alloc((size_t)(N + 1) * 4);
    int* bsum   = (int*)alloc((size_t)256 * 4);
    int* bcur   = (int*)alloc((size_t)NBK * NSUB * CPAD * 4);
    unsigned int* bkt = (unsigned int*)alloc((size_t)NBK * NSUB * BSUBCAP * 4);
    int* scol   = (int*)alloc((size_t)E * 4);
    float* Wc2t = (float*)alloc((size_t)8 * 128 * 4);
    float* s2   = (float*)alloc((size_t)N * 2 * 4);
    float* w2   = (float*)alloc((size_t)N * 2 * 4);

    hipMemsetAsync(bcur, 0, (size_t)NBK * NSUB * CPAD * 4, stream);

    int gE = (E + 255) / 256;
    int gN = (N + 255) / 256;
    int NB = (N + 1023) / 1024;

    // conversions
    k_xb<<<(N * (KP / 8) + 255) / 256, 256, 0, stream>>>(x, xb, N);
    k_wbt<<<(NCOLS * (KP / 8) + 255) / 256, 256, 0, stream>>>(W1, wbt);
    k_wc2t<<<4, 256, 0, stream>>>(W2, Wc2t);

    // CSR build (XCD-local sub-buckets)
    k_bucket<<<gE, 256, 0, stream>>>(erow, ecol, bcur, bkt, E);
    k_hist<<<NBK, 256, 0, stream>>>(bcur, bkt, cnt, dis, N);
    k_scan1<<<NB, 256, 0, stream>>>(cnt, off, bsum, N);
    k_scan2<<<1, 256, 0, stream>>>(bsum, NB);
    k_scan3<<<gN, 256, 0, stream>>>(off, bsum, N, E);
    k_emit<<<NBK, 256, 0, stream>>>(bcur, bkt, off, scol, N);

    // layer 1: MFMA GEMM (g fast-varying for xb L2 reuse)
    dim3 g1(3, (N + 127) / 128);
    k_gemm1_mfma<<<g1, 256, 0, stream>>>(xb, wbt, dis, ub, sA, wb, N);

    int nw4 = (N + 3) / 4;
    int gP4 = (nw4 * 64 + 255) / 256;
    // sb = bf16( sA - 2*dis^2 * prop-sum(wb) )
    k_prop_b2b<<<gP4, 256, 0, stream>>>(off, scol, wb, sA, dis, sb, N);
    // fused: h = relu(ub - dis*prop-sum(sb) + b1); out/s2/w2 = h @ W2
    k_prop_b2f_gemm2<<<gP4, 256, 0, stream>>>(off, scol, sb, ub, dis, b1,
                                              Wc2t, b2, out, s2, w2, N);

    // layer 2 props (2-wide)
    k_prop2_csr<<<gN, 256, 0, stream>>>(off, scol, w2, s2, dis, s2, 1, N);
    k_prop2_csr<<<gN, 256, 0, stream>>>(off, scol, s2, out, dis, out, 0, N);
}

// Round 15
// 633.534 us; speedup vs baseline: 1.1968x; 1.0463x over previous
//
#include <hip/hip_runtime.h>
#include <hip/hip_bf16.h>
#include <stdint.h>

#define NF 165
#define NH 128
#define KP 192          // padded K for MFMA
#define NCOLS 384
#define BSH 8           // rows per bucket = 256
#define BROWS 256
#define BCAP 6144       // whole-bucket capacity for emit LDS buffer
#define NSUB 8          // sub-buckets per bucket (one per XCD)
#define BSUBCAP 768     // per-(bucket,xcd) capacity (mean 512, +11 sigma)
#define CPAD 16         // cursor padding: 16 ints = 64B line

typedef __attribute__((ext_vector_type(8))) short bf16x8;
typedef __attribute__((ext_vector_type(4))) float f32x4;

// ---- bf16 helpers --------------------------------------------------------

__device__ __forceinline__ unsigned short f2bf(float f) {
    unsigned int u = __builtin_bit_cast(unsigned int, f);
    u = (u + 0x7FFFu + ((u >> 16) & 1u)) >> 16;   // RNE
    return (unsigned short)u;
}
__device__ __forceinline__ float bf2f_lo(unsigned int v) {
    return __builtin_bit_cast(float, v << 16);
}
__device__ __forceinline__ float bf2f_hi(unsigned int v) {
    return __builtin_bit_cast(float, v & 0xFFFF0000u);
}

// accumulate a uint4 of bf16 pairs into acc[8]
#define ACC8(acc, v)                                                   \
    {                                                                  \
        unsigned _vv[4] = {(v).x, (v).y, (v).z, (v).w};                \
        _Pragma("unroll") for (int _j = 0; _j < 4; ++_j) {             \
            acc[2 * _j] += bf2f_lo(_vv[_j]);                           \
            acc[2 * _j + 1] += bf2f_hi(_vv[_j]);                       \
        }                                                              \
    }

// ---- CSR build ----------------------------------------------------------

// Level-1: append edges to XCD-local sub-buckets. NT loads only here: the
// 25.6MB edge stream is coalesced single-use; keeping it out of L2 preserves
// sub-bucket head lines + cursors -> full-line writebacks.
__global__ __launch_bounds__(256) void k_bucket(
        const int* __restrict__ erow, const int* __restrict__ ecol,
        int* __restrict__ bcur, unsigned int* __restrict__ bkt, int E) {
    int e = blockIdx.x * 256 + threadIdx.x;
    if (e >= E) return;
    int x = blockIdx.x & (NSUB - 1);
    int r = __builtin_nontemporal_load(erow + e);
    int c = __builtin_nontemporal_load(ecol + e);
    int sub = (r >> BSH) * NSUB + x;
    int pos = atomicAdd(&bcur[sub * CPAD], 1);
    if (pos < BSUBCAP)
        bkt[(size_t)sub * BSUBCAP + pos] =
            ((unsigned)(r & (BROWS - 1)) << 18) | (unsigned)c;
}

// Histogram bucket records -> cnt + dis (fused).
__global__ __launch_bounds__(256) void k_hist(
        const int* __restrict__ bcur, const unsigned int* __restrict__ bkt,
        int* __restrict__ cnt, float* __restrict__ dis, int N) {
    __shared__ int h[BROWS];
    int b = blockIdx.x;
    int t = threadIdx.x;
    h[t] = 0;
    __syncthreads();
#pragma unroll
    for (int x = 0; x < NSUB; ++x) {
        int sub = b * NSUB + x;
        int nb = bcur[sub * CPAD];
        if (nb > BSUBCAP) nb = BSUBCAP;
        const unsigned int* src = bkt + (size_t)sub * BSUBCAP;
        for (int i = t; i < nb; i += 256)
            atomicAdd(&h[__builtin_nontemporal_load(src + i) >> 18], 1);
    }
    __syncthreads();
    int base = b << BSH;
    if (base + t < N) {
        int d = h[t];
        cnt[base + t] = d;
        dis[base + t] = (d > 0) ? rsqrtf((float)d) : 0.0f;
    }
}

__global__ __launch_bounds__(256) void k_scan1(
        const int* __restrict__ cnt, int* __restrict__ off,
        int* __restrict__ bsum, int N) {
    __shared__ int sh[256];
    int t = threadIdx.x;
    int base = blockIdx.x * 1024 + t * 4;
    int v0 = (base + 0 < N) ? cnt[base + 0] : 0;
    int v1 = (base + 1 < N) ? cnt[base + 1] : 0;
    int v2 = (base + 2 < N) ? cnt[base + 2] : 0;
    int v3 = (base + 3 < N) ? cnt[base + 3] : 0;
    int tsum = v0 + v1 + v2 + v3;
    sh[t] = tsum;
    __syncthreads();
#pragma unroll
    for (int ofs = 1; ofs < 256; ofs <<= 1) {
        int x = (t >= ofs) ? sh[t - ofs] : 0;
        __syncthreads();
        sh[t] += x;
        __syncthreads();
    }
    int excl = sh[t] - tsum;
    if (t == 255) bsum[blockIdx.x] = sh[t];
    if (base + 0 < N) off[base + 0] = excl;
    excl += v0;
    if (base + 1 < N) off[base + 1] = excl;
    excl += v1;
    if (base + 2 < N) off[base + 2] = excl;
    excl += v2;
    if (base + 3 < N) off[base + 3] = excl;
}

__global__ __launch_bounds__(256) void k_scan2(int* __restrict__ bsum, int NB) {
    __shared__ int sh[256];
    int t = threadIdx.x;
    int v = (t < NB) ? bsum[t] : 0;
    sh[t] = v;
    __syncthreads();
#pragma unroll
    for (int ofs = 1; ofs < 256; ofs <<= 1) {
        int x = (t >= ofs) ? sh[t - ofs] : 0;
        __syncthreads();
        sh[t] += x;
        __syncthreads();
    }
    if (t < NB) bsum[t] = sh[t] - v;
}

__global__ __launch_bounds__(256) void k_scan3(
        int* __restrict__ off, const int* __restrict__ bsum, int N, int E) {
    int i = blockIdx.x * 256 + threadIdx.x;
    if (i >= N) return;
    off[i] = off[i] + bsum[i >> 10];
    if (i == 0) off[N] = E;
}

// Level-2: one block per bucket; place edges at exact CSR slots via LDS,
// then stream out coalesced.
__global__ __launch_bounds__(256) void k_emit(
        const int* __restrict__ bcur, const unsigned int* __restrict__ bkt,
        const int* __restrict__ off, int* __restrict__ scol, int N) {
    __shared__ unsigned colbuf[BCAP];
    __shared__ int rowoff[BROWS + 1];
    __shared__ int cursor[BROWS];

    int b = blockIdx.x;
    int base = b << BSH;
    int nrows = N - base;
    if (nrows > BROWS) nrows = BROWS;
    int t = threadIdx.x;

    for (int i = t; i <= nrows; i += 256) rowoff[i] = off[base + i];
    if (t < BROWS) cursor[t] = 0;
    __syncthreads();

    int regionStart = rowoff[0];
    int total = rowoff[nrows] - regionStart;

#pragma unroll
    for (int x = 0; x < NSUB; ++x) {
        int sub = b * NSUB + x;
        int nb = bcur[sub * CPAD];
        if (nb > BSUBCAP) nb = BSUBCAP;
        const unsigned int* src = bkt + (size_t)sub * BSUBCAP;
        for (int i = t; i < nb; i += 256) {
            unsigned v = __builtin_nontemporal_load(src + i);
            int rl = v >> 18;
            unsigned c = v & 0x3FFFFu;
            int pos = (rowoff[rl] - regionStart) + atomicAdd(&cursor[rl], 1);
            if (pos < BCAP) colbuf[pos] = c;
        }
    }
    __syncthreads();

    for (int i = t; i < total; i += 256) scol[regionStart + i] = (int)colbuf[i];
}

// ---- conversions ---------------------------------------------------------

__global__ __launch_bounds__(256) void k_xb(
        const float* __restrict__ x, unsigned short* __restrict__ xb, int N) {
    int gid = blockIdx.x * 256 + threadIdx.x;
    if (gid >= N * (KP / 8)) return;
    int row = gid / (KP / 8);
    int k0 = (gid % (KP / 8)) * 8;
    unsigned short v[8];
#pragma unroll
    for (int i = 0; i < 8; ++i) {
        int k = k0 + i;
        v[i] = (k < NF) ? f2bf(x[(size_t)row * NF + k]) : (unsigned short)0;
    }
    uint4 pk;
    pk.x = (unsigned)v[0] | ((unsigned)v[1] << 16);
    pk.y = (unsigned)v[2] | ((unsigned)v[3] << 16);
    pk.z = (unsigned)v[4] | ((unsigned)v[5] << 16);
    pk.w = (unsigned)v[6] | ((unsigned)v[7] << 16);
    *(uint4*)(xb + (size_t)row * KP + k0) = pk;
}

__global__ __launch_bounds__(256) void k_wbt(
        const float* __restrict__ W1, unsigned short* __restrict__ wbt) {
    int gid = blockIdx.x * 256 + threadIdx.x;
    if (gid >= NCOLS * (KP / 8)) return;
    int col = gid / (KP / 8);
    int k0 = (gid % (KP / 8)) * 8;
    int cc = col & 127;
    unsigned short v[8];
#pragma unroll
    for (int i = 0; i < 8; ++i) {
        int k = k0 + i;
        float f = 0.0f;
        if (k < NF) {
            if (col < 128)      f = W1[k * 128 + cc] - W1[42240 + k * 128 + cc];
            else if (col < 256) f = W1[21120 + k * 128 + cc];
            else                f = W1[42240 + k * 128 + cc];
        }
        v[i] = f2bf(f);
    }
    uint4 pk;
    pk.x = (unsigned)v[0] | ((unsigned)v[1] << 16);
    pk.y = (unsigned)v[2] | ((unsigned)v[3] << 16);
    pk.z = (unsigned)v[4] | ((unsigned)v[5] << 16);
    pk.w = (unsigned)v[6] | ((unsigned)v[7] << 16);
    *(uint4*)(wbt + (size_t)col * KP + k0) = pk;
}

// Wc2t[8][128] TRANSPOSED: row t (output col), col k (hidden).
__global__ __launch_bounds__(256) void k_wc2t(const float* __restrict__ W2,
                                              float* __restrict__ Wc2t) {
    int gid = blockIdx.x * 256 + threadIdx.x;
    if (gid >= 8 * 128) return;
    int t = gid >> 7;
    int k = gid & 127;
    float v = 0.0f;
    if (t < 2)      v = W2[k * 2 + t] - W2[512 + k * 2 + t];
    else if (t < 4) v = W2[256 + k * 2 + (t - 2)];
    else if (t < 6) v = W2[512 + k * 2 + (t - 4)];
    Wc2t[gid] = v;
}

// ---- GEMM1 via MFMA ------------------------------------------------------
// XCD-local panel swizzle: bid&7 = XCD; each XCD runs all 3 col-groups of
// its panels consecutively -> xb panel fetched once into that XCD's L2.
// g==0 -> ub = u (bf16); g==1 -> sA = dis*s (bf16); g==2 -> wb = dis*w (bf16)
__global__ __launch_bounds__(256) void k_gemm1_mfma(
        const unsigned short* __restrict__ xb, const unsigned short* __restrict__ wbt,
        const float* __restrict__ dis,
        unsigned int* __restrict__ ub, unsigned int* __restrict__ sA,
        unsigned int* __restrict__ wb, int N, int P) {
    int xcd = blockIdx.x & 7;
    int wrk = blockIdx.x >> 3;
    int p = xcd + 8 * (wrk / 3);
    int g = wrk - 3 * (wrk / 3);
    if (p >= P) return;

    __shared__ unsigned short As[128][40];
    __shared__ unsigned short Bs[128][40];

    int tid = threadIdx.x;
    int w = tid >> 6;
    int lane = tid & 63;
    int l15 = lane & 15;
    int l16 = lane >> 4;
    int brow = p * 128;
    int gcol = g * 128;

    int sr = tid >> 1;
    int sk = (tid & 1) * 16;

    f32x4 acc[2][8] = {};

    for (int kc = 0; kc < 6; ++kc) {
        int k0 = kc * 32;
        uint4 va0 = {0, 0, 0, 0}, va1 = {0, 0, 0, 0};
        if (brow + sr < N) {
            const unsigned short* asrc = xb + (size_t)(brow + sr) * KP + k0 + sk;
            va0 = *(const uint4*)asrc;
            va1 = *(const uint4*)(asrc + 8);
        }
        const unsigned short* bsrc = wbt + (size_t)(gcol + sr) * KP + k0 + sk;
        uint4 vb0 = *(const uint4*)bsrc;
        uint4 vb1 = *(const uint4*)(bsrc + 8);
        __syncthreads();
        *(uint4*)&As[sr][sk] = va0;
        *(uint4*)&As[sr][sk + 8] = va1;
        *(uint4*)&Bs[sr][sk] = vb0;
        *(uint4*)&Bs[sr][sk + 8] = vb1;
        __syncthreads();

        bf16x8 a[2], b[8];
#pragma unroll
        for (int m = 0; m < 2; ++m)
            a[m] = *(const bf16x8*)&As[w * 32 + m * 16 + l15][l16 * 8];
#pragma unroll
        for (int n = 0; n < 8; ++n)
            b[n] = *(const bf16x8*)&Bs[n * 16 + l15][l16 * 8];
#pragma unroll
        for (int m = 0; m < 2; ++m)
#pragma unroll
            for (int n = 0; n < 8; ++n)
                acc[m][n] = __builtin_amdgcn_mfma_f32_16x16x32_bf16(
                    a[m], b[n], acc[m][n], 0, 0, 0);
    }

    unsigned int* dst = (g == 0) ? ub : (g == 1) ? sA : wb;
#pragma unroll
    for (int m = 0; m < 2; ++m) {
#pragma unroll
        for (int reg = 0; reg < 4; ++reg) {
            int row = brow + w * 32 + m * 16 + l16 * 4 + reg;
            if (row >= N) continue;
            float sc = (g == 0) ? 1.0f : dis[row];
#pragma unroll
            for (int n = 0; n < 4; ++n) {
                int c = n * 16 + l15;
                float lo = sc * acc[m][n][reg];
                float hi = sc * acc[m][n + 4][reg];
                dst[(size_t)row * 64 + c] =
                    (unsigned)f2bf(lo) | ((unsigned)f2bf(hi) << 16);
            }
        }
    }
}

// ---- 128-wide props: 4 rows/wave, 16 lanes/row, uint4 gathers, unroll-4 ---

// sb[r] = bf16( sA[r] - 2*dis[r]^2 * sum_e wb[col] )
__global__ __launch_bounds__(256) void k_prop_b2b(
        const int* __restrict__ off, const int* __restrict__ scol,
        const unsigned int* __restrict__ srcb, const unsigned int* __restrict__ addb,
        const float* __restrict__ dis, unsigned int* __restrict__ dstb, int N) {
    int wid = (blockIdx.x * 256 + threadIdx.x) >> 6;
    int lane = threadIdx.x & 63;
    int g = lane >> 4, q = lane & 15;
    int r = wid * 4 + g;
    if (r >= N) return;
    int e = off[r], end = off[r + 1];
    const uint4* src4 = (const uint4*)srcb;
    float a[8] = {}, b[8] = {};
    for (; e + 4 <= end; e += 4) {
        int c0 = scol[e], c1 = scol[e + 1], c2 = scol[e + 2], c3 = scol[e + 3];
        uint4 v0 = src4[(size_t)c0 * 16 + q];
        uint4 v1 = src4[(size_t)c1 * 16 + q];
        uint4 v2 = src4[(size_t)c2 * 16 + q];
        uint4 v3 = src4[(size_t)c3 * 16 + q];
        ACC8(a, v0);
        ACC8(b, v1);
        ACC8(a, v2);
        ACC8(b, v3);
    }
    for (; e < end; ++e) {
        int c0 = scol[e];
        uint4 v0 = src4[(size_t)c0 * 16 + q];
        ACC8(a, v0);
    }
    float d = dis[r];
    float m2 = -2.0f * d * d;
    uint4 ad = ((const uint4*)addb)[(size_t)r * 16 + q];
    unsigned adp[4] = {ad.x, ad.y, ad.z, ad.w};
    uint4 o;
    unsigned* op = (unsigned*)&o;
#pragma unroll
    for (int j = 0; j < 4; ++j) {
        float lo = bf2f_lo(adp[j]) + m2 * (a[2 * j] + b[2 * j]);
        float hi = bf2f_hi(adp[j]) + m2 * (a[2 * j + 1] + b[2 * j + 1]);
        op[j] = (unsigned)f2bf(lo) | ((unsigned)f2bf(hi) << 16);
    }
    ((uint4*)dstb)[(size_t)r * 16 + q] = o;
}

// Fused: h = relu(ub - dis*prop(sb) + b1) in registers, contracted with
// Wc2t (transposed LDS: Ws[t*128+c], bank = c%32 -> 2-way only, free).
__global__ __launch_bounds__(256) void k_prop_b2f_gemm2(
        const int* __restrict__ off, const int* __restrict__ scol,
        const unsigned int* __restrict__ srcb, const unsigned int* __restrict__ addb,
        const float* __restrict__ dis, const float* __restrict__ b1,
        const float* __restrict__ Wc2t, const float* __restrict__ b2,
        float* __restrict__ out, float* __restrict__ s2, float* __restrict__ w2,
        int N) {
    __shared__ float Ws[8 * 128];
    int tid = threadIdx.x;
    for (int idx = tid; idx < 8 * 128; idx += 256) Ws[idx] = Wc2t[idx];
    __syncthreads();

    int wid = (blockIdx.x * 256 + tid) >> 6;
    int lane = tid & 63;
    int g = lane >> 4, q = lane & 15;
    int r = wid * 4 + g;
    if (r >= N) return;

    float blo[4], bhi[4];
#pragma unroll
    for (int j = 0; j < 4; ++j) {
        blo[j] = b1[q * 4 + j];
        bhi[j] = b1[q * 4 + j + 64];
    }

    int e = off[r], end = off[r + 1];
    const uint4* src4 = (const uint4*)srcb;
    float a[8] = {}, b[8] = {};
    for (; e + 4 <= end; e += 4) {
        int c0 = scol[e], c1 = scol[e + 1], c2 = scol[e + 2], c3 = scol[e + 3];
        uint4 v0 = src4[(size_t)c0 * 16 + q];
        uint4 v1 = src4[(size_t)c1 * 16 + q];
        uint4 v2 = src4[(size_t)c2 * 16 + q];
        uint4 v3 = src4[(size_t)c3 * 16 + q];
        ACC8(a, v0);
        ACC8(b, v1);
        ACC8(a, v2);
        ACC8(b, v3);
    }
    for (; e < end; ++e) {
        int c0 = scol[e];
        uint4 v0 = src4[(size_t)c0 * 16 + q];
        ACC8(a, v0);
    }
    float m1 = -dis[r];
    uint4 ad = ((const uint4*)addb)[(size_t)r * 16 + q];
    unsigned adp[4] = {ad.x, ad.y, ad.z, ad.w};
    float acc[6] = {};
#pragma unroll
    for (int j = 0; j < 4; ++j) {
        int c = q * 4 + j;
        float lo = fmaxf(bf2f_lo(adp[j]) + m1 * (a[2 * j] + b[2 * j]) + blo[j], 0.0f);
        float hi = fmaxf(bf2f_hi(adp[j]) + m1 * (a[2 * j + 1] + b[2 * j + 1]) + bhi[j], 0.0f);
#pragma unroll
        for (int t = 0; t < 6; ++t)
            acc[t] += lo * Ws[t * 128 + c] + hi * Ws[t * 128 + c + 64];
    }
#pragma unroll
    for (int ofs = 8; ofs; ofs >>= 1) {
#pragma unroll
        for (int t = 0; t < 6; ++t)
            acc[t] += __shfl_xor(acc[t], ofs);
    }
    if (q == 0) {
        float d = dis[r];
        out[(size_t)r * 2 + 0] = acc[0] + b2[0];
        out[(size_t)r * 2 + 1] = acc[1] + b2[1];
        s2[(size_t)r * 2 + 0] = d * acc[2];
        s2[(size_t)r * 2 + 1] = d * acc[3];
        w2[(size_t)r * 2 + 0] = d * acc[4];
        w2[(size_t)r * 2 + 1] = d * acc[5];
    }
}

// CSR prop, 2-wide: dst[r] = add[r] + m * sum src[col], m = sq ? -2*dis^2 : -dis.
__global__ __launch_bounds__(256) void k_prop2_csr(
        const int* __restrict__ off, const int* __restrict__ scol,
        const float* __restrict__ src, const float* __restrict__ add,
        const float* __restrict__ dis, float* __restrict__ dst,
        int sq, int N) {
    int r = blockIdx.x * 256 + threadIdx.x;
    if (r >= N) return;
    int e0 = off[r], e1 = off[r + 1];
    float a0 = 0.0f, a1 = 0.0f, b0 = 0.0f, b1v = 0.0f;
    int e = e0;
    for (; e + 2 <= e1; e += 2) {
        int c0 = scol[e], c1 = scol[e + 1];
        float2 v0 = *(const float2*)(src + (size_t)c0 * 2);
        float2 v1 = *(const float2*)(src + (size_t)c1 * 2);
        a0 += v0.x; a1 += v0.y;
        b0 += v1.x; b1v += v1.y;
    }
    if (e < e1) {
        int c0 = scol[e];
        float2 v0 = *(const float2*)(src + (size_t)c0 * 2);
        a0 += v0.x; a1 += v0.y;
    }
    a0 += b0; a1 += b1v;
    float d = dis[r];
    float m = sq ? (-2.0f * d * d) : (-d);
    float2 ad = *(const float2*)(add + (size_t)r * 2);
    float2 o = {ad.x + m * a0, ad.y + m * a1};
    *(float2*)(dst + (size_t)r * 2) = o;
}

extern "C" void kernel_launch(void* const* d_in, const int* in_sizes, int n_in,
                              void* d_out, int out_size, void* d_ws, size_t ws_size,
                              hipStream_t stream) {
    const float* x   = (const float*)d_in[0];
    const int* eidx  = (const int*)d_in[1];
    const float* W1  = (const float*)d_in[2];
    const float* b1  = (const float*)d_in[3];
    const float* W2  = (const float*)d_in[4];
    const float* b2  = (const float*)d_in[5];
    float* out       = (float*)d_out;

    int N = in_sizes[0] / NF;
    int E = in_sizes[1] / 2;
    const int* erow = eidx;
    const int* ecol = eidx + E;
    int NBK = (N + BROWS - 1) >> BSH;

    char* p = (char*)d_ws;
    auto alloc = [&](size_t bytes) {
        char* q = p;
        p += (bytes + 255) & ~(size_t)255;
        return q;
    };
    unsigned int* ub = (unsigned int*)alloc((size_t)N * 64 * 4);
    unsigned int* sA = (unsigned int*)alloc((size_t)N * 64 * 4);
    unsigned int* wb = (unsigned int*)alloc((size_t)N * 64 * 4);
    unsigned int* sb = (unsigned int*)alloc((size_t)N * 64 * 4);
    unsigned short* xb  = (unsigned short*)alloc((size_t)N * KP * 2);
    unsigned short* wbt = (unsigned short*)alloc((size_t)NCOLS * KP * 2);
    float* dis  = (float*)alloc((size_t)N * 4);
    int* cnt    = (int*)alloc((size_t)N * 4);
    int* off    = (int*)alloc((size_t)(N + 1) * 4);
    int* bsum   = (int*)alloc((size_t)256 * 4);
    int* bcur   = (int*)alloc((size_t)NBK * NSUB * CPAD * 4);
    unsigned int* bkt = (unsigned int*)alloc((size_t)NBK * NSUB * BSUBCAP * 4);
    int* scol   = (int*)alloc((size_t)E * 4);
    float* Wc2t = (float*)alloc((size_t)8 * 128 * 4);
    float* s2   = (float*)alloc((size_t)N * 2 * 4);
    float* w2   = (float*)alloc((size_t)N * 2 * 4);

    hipMemsetAsync(bcur, 0, (size_t)NBK * NSUB * CPAD * 4, stream);

    int gE = (E + 255) / 256;
    int gN = (N + 255) / 256;
    int NB = (N + 1023) / 1024;

    // conversions
    k_xb<<<(N * (KP / 8) + 255) / 256, 256, 0, stream>>>(x, xb, N);
    k_wbt<<<(NCOLS * (KP / 8) + 255) / 256, 256, 0, stream>>>(W1, wbt);
    k_wc2t<<<4, 256, 0, stream>>>(W2, Wc2t);

    // CSR build (XCD-local sub-buckets)
    k_bucket<<<gE, 256, 0, stream>>>(erow, ecol, bcur, bkt, E);
    k_hist<<<NBK, 256, 0, stream>>>(bcur, bkt, cnt, dis, N);
    k_scan1<<<NB, 256, 0, stream>>>(cnt, off, bsum, N);
    k_scan2<<<1, 256, 0, stream>>>(bsum, NB);
    k_scan3<<<gN, 256, 0, stream>>>(off, bsum, N, E);
    k_emit<<<NBK, 256, 0, stream>>>(bcur, bkt, off, scol, N);

    // layer 1: MFMA GEMM with XCD-local panel swizzle
    int P = (N + 127) / 128;
    int wPerX = 3 * ((P + 7) / 8);      // works per XCD (3 col-groups/panel)
    k_gemm1_mfma<<<8 * wPerX, 256, 0, stream>>>(xb, wbt, dis, ub, sA, wb, N, P);

    int nw4 = (N + 3) / 4;
    int gP4 = (nw4 * 64 + 255) / 256;
    // sb = bf16( sA - 2*dis^2 * prop-sum(wb) )
    k_prop_b2b<<<gP4, 256, 0, stream>>>(off, scol, wb, sA, dis, sb, N);
    // fused: h = relu(ub - dis*prop-sum(sb) + b1); out/s2/w2 = h @ W2
    k_prop_b2f_gemm2<<<gP4, 256, 0, stream>>>(off, scol, sb, ub, dis, b1,
                                              Wc2t, b2, out, s2, w2, N);

    // layer 2 props (2-wide)
    k_prop2_csr<<<gN, 256, 0, stream>>>(off, scol, w2, s2, dis, s2, 1, N);
    k_prop2_csr<<<gN, 256, 0, stream>>>(off, scol, s2, out, dis, out, 0, N);
}

// Round 16
// 546.965 us; speedup vs baseline: 1.3862x; 1.1583x over previous
//
#include <hip/hip_runtime.h>
#include <hip/hip_bf16.h>
#include <stdint.h>

#define NF 165
#define NH 128
#define KP 192          // padded K for MFMA
#define NCOLS 384
#define BSH 8           // rows per bucket = 256
#define BROWS 256
#define BCAP 6144       // whole-bucket capacity for emit LDS buffer
#define NSUB 8          // sub-buckets per bucket (one per XCD)
#define BSUBCAP 768     // per-(bucket,xcd) capacity (mean 512, +11 sigma)
#define CPAD 16         // cursor padding: 16 ints = 64B line
#define TILE 8192       // edges per bucket-pass block
#define NBKMAX 1024     // padded bucket count for block scan

typedef __attribute__((ext_vector_type(8))) short bf16x8;
typedef __attribute__((ext_vector_type(4))) float f32x4;

// ---- bf16 helpers --------------------------------------------------------

__device__ __forceinline__ unsigned short f2bf(float f) {
    unsigned int u = __builtin_bit_cast(unsigned int, f);
    u = (u + 0x7FFFu + ((u >> 16) & 1u)) >> 16;   // RNE
    return (unsigned short)u;
}
__device__ __forceinline__ float bf2f_lo(unsigned int v) {
    return __builtin_bit_cast(float, v << 16);
}
__device__ __forceinline__ float bf2f_hi(unsigned int v) {
    return __builtin_bit_cast(float, v & 0xFFFF0000u);
}

// accumulate a uint4 of bf16 pairs into acc[8]
#define ACC8(acc, v)                                                   \
    {                                                                  \
        unsigned _vv[4] = {(v).x, (v).y, (v).z, (v).w};                \
        _Pragma("unroll") for (int _j = 0; _j < 4; ++_j) {             \
            acc[2 * _j] += bf2f_lo(_vv[_j]);                           \
            acc[2 * _j + 1] += bf2f_hi(_vv[_j]);                       \
        }                                                              \
    }

// ---- CSR build ----------------------------------------------------------

// Radix-partition bucket pass. Per 8192-edge tile: LDS histogram ->
// block scan -> ONE cursor reservation per touched (bucket, xcd) ->
// rank into LDS stage (sorted by bucket) -> coalesced contiguous write-out.
// Kills the 4B-scatter write-through amplification (r15: 114MB for 13MB).
__global__ __launch_bounds__(256) void k_bucket(
        const int* __restrict__ erow, const int* __restrict__ ecol,
        int* __restrict__ bcur, unsigned int* __restrict__ bkt, int E) {
    __shared__ int hist[NBKMAX];
    __shared__ int basex[NBKMAX];
    __shared__ int gbase[NBKMAX];
    __shared__ int cur[NBKMAX];
    __shared__ int scanbuf[256];
    __shared__ unsigned stage[TILE];
    __shared__ unsigned short bof[TILE];

    int t = threadIdx.x;
    int x = blockIdx.x & (NSUB - 1);
    int e0 = blockIdx.x * TILE;
    int cnt = E - e0;
    if (cnt > TILE) cnt = TILE;
    if (cnt <= 0) return;

    for (int i = t; i < NBKMAX; i += 256) { hist[i] = 0; cur[i] = 0; }
    __syncthreads();

    // Phase A: histogram
    for (int i = t; i < cnt; i += 256) {
        int r = __builtin_nontemporal_load(erow + e0 + i);
        atomicAdd(&hist[r >> BSH], 1);
    }
    __syncthreads();

    // Phase B: block exclusive scan (4 buckets/thread) + global reservation
    int b0 = 4 * t;
    int h0 = hist[b0], h1 = hist[b0 + 1], h2 = hist[b0 + 2], h3 = hist[b0 + 3];
    int tsum = h0 + h1 + h2 + h3;
    scanbuf[t] = tsum;
    __syncthreads();
#pragma unroll
    for (int ofs = 1; ofs < 256; ofs <<= 1) {
        int v = (t >= ofs) ? scanbuf[t - ofs] : 0;
        __syncthreads();
        scanbuf[t] += v;
        __syncthreads();
    }
    int excl = scanbuf[t] - tsum;
    basex[b0] = excl;
    basex[b0 + 1] = excl + h0;
    basex[b0 + 2] = excl + h0 + h1;
    basex[b0 + 3] = excl + h0 + h1 + h2;
    int hb[4] = {h0, h1, h2, h3};
#pragma unroll
    for (int j = 0; j < 4; ++j) {
        int b = b0 + j;
        if (hb[j] > 0)
            gbase[b] = atomicAdd(&bcur[(b * NSUB + x) * CPAD], hb[j]);
    }
    __syncthreads();

    // Phase C: rank edges into bucket-sorted LDS stage
    for (int i = t; i < cnt; i += 256) {
        int r = __builtin_nontemporal_load(erow + e0 + i);
        int c = __builtin_nontemporal_load(ecol + e0 + i);
        int b = r >> BSH;
        int rk = atomicAdd(&cur[b], 1);
        int pos = basex[b] + rk;
        stage[pos] = ((unsigned)(r & (BROWS - 1)) << 18) | (unsigned)c;
        bof[pos] = (unsigned short)b;
    }
    __syncthreads();

    // Phase D: coalesced write-out (contiguous run per bucket)
    for (int i = t; i < cnt; i += 256) {
        int b = bof[i];
        int slot = gbase[b] + (i - basex[b]);
        if (slot < BSUBCAP)
            bkt[(size_t)(b * NSUB + x) * BSUBCAP + slot] = stage[i];
    }
}

// Histogram bucket records -> cnt + dis (fused).
__global__ __launch_bounds__(256) void k_hist(
        const int* __restrict__ bcur, const unsigned int* __restrict__ bkt,
        int* __restrict__ cnt, float* __restrict__ dis, int N) {
    __shared__ int h[BROWS];
    int b = blockIdx.x;
    int t = threadIdx.x;
    h[t] = 0;
    __syncthreads();
#pragma unroll
    for (int x = 0; x < NSUB; ++x) {
        int sub = b * NSUB + x;
        int nb = bcur[sub * CPAD];
        if (nb > BSUBCAP) nb = BSUBCAP;
        const unsigned int* src = bkt + (size_t)sub * BSUBCAP;
        for (int i = t; i < nb; i += 256)
            atomicAdd(&h[__builtin_nontemporal_load(src + i) >> 18], 1);
    }
    __syncthreads();
    int base = b << BSH;
    if (base + t < N) {
        int d = h[t];
        cnt[base + t] = d;
        dis[base + t] = (d > 0) ? rsqrtf((float)d) : 0.0f;
    }
}

__global__ __launch_bounds__(256) void k_scan1(
        const int* __restrict__ cnt, int* __restrict__ off,
        int* __restrict__ bsum, int N) {
    __shared__ int sh[256];
    int t = threadIdx.x;
    int base = blockIdx.x * 1024 + t * 4;
    int v0 = (base + 0 < N) ? cnt[base + 0] : 0;
    int v1 = (base + 1 < N) ? cnt[base + 1] : 0;
    int v2 = (base + 2 < N) ? cnt[base + 2] : 0;
    int v3 = (base + 3 < N) ? cnt[base + 3] : 0;
    int tsum = v0 + v1 + v2 + v3;
    sh[t] = tsum;
    __syncthreads();
#pragma unroll
    for (int ofs = 1; ofs < 256; ofs <<= 1) {
        int x = (t >= ofs) ? sh[t - ofs] : 0;
        __syncthreads();
        sh[t] += x;
        __syncthreads();
    }
    int excl = sh[t] - tsum;
    if (t == 255) bsum[blockIdx.x] = sh[t];
    if (base + 0 < N) off[base + 0] = excl;
    excl += v0;
    if (base + 1 < N) off[base + 1] = excl;
    excl += v1;
    if (base + 2 < N) off[base + 2] = excl;
    excl += v2;
    if (base + 3 < N) off[base + 3] = excl;
}

__global__ __launch_bounds__(256) void k_scan2(int* __restrict__ bsum, int NB) {
    __shared__ int sh[256];
    int t = threadIdx.x;
    int v = (t < NB) ? bsum[t] : 0;
    sh[t] = v;
    __syncthreads();
#pragma unroll
    for (int ofs = 1; ofs < 256; ofs <<= 1) {
        int x = (t >= ofs) ? sh[t - ofs] : 0;
        __syncthreads();
        sh[t] += x;
        __syncthreads();
    }
    if (t < NB) bsum[t] = sh[t] - v;
}

__global__ __launch_bounds__(256) void k_scan3(
        int* __restrict__ off, const int* __restrict__ bsum, int N, int E) {
    int i = blockIdx.x * 256 + threadIdx.x;
    if (i >= N) return;
    off[i] = off[i] + bsum[i >> 10];
    if (i == 0) off[N] = E;
}

// Level-2: one block per bucket; place edges at exact CSR slots via LDS,
// then stream out coalesced.
__global__ __launch_bounds__(256) void k_emit(
        const int* __restrict__ bcur, const unsigned int* __restrict__ bkt,
        const int* __restrict__ off, int* __restrict__ scol, int N) {
    __shared__ unsigned colbuf[BCAP];
    __shared__ int rowoff[BROWS + 1];
    __shared__ int cursor[BROWS];

    int b = blockIdx.x;
    int base = b << BSH;
    int nrows = N - base;
    if (nrows > BROWS) nrows = BROWS;
    int t = threadIdx.x;

    for (int i = t; i <= nrows; i += 256) rowoff[i] = off[base + i];
    if (t < BROWS) cursor[t] = 0;
    __syncthreads();

    int regionStart = rowoff[0];
    int total = rowoff[nrows] - regionStart;

#pragma unroll
    for (int x = 0; x < NSUB; ++x) {
        int sub = b * NSUB + x;
        int nb = bcur[sub * CPAD];
        if (nb > BSUBCAP) nb = BSUBCAP;
        const unsigned int* src = bkt + (size_t)sub * BSUBCAP;
        for (int i = t; i < nb; i += 256) {
            unsigned v = __builtin_nontemporal_load(src + i);
            int rl = v >> 18;
            unsigned c = v & 0x3FFFFu;
            int pos = (rowoff[rl] - regionStart) + atomicAdd(&cursor[rl], 1);
            if (pos < BCAP) colbuf[pos] = c;
        }
    }
    __syncthreads();

    for (int i = t; i < total; i += 256) scol[regionStart + i] = (int)colbuf[i];
}

// ---- conversions ---------------------------------------------------------

__global__ __launch_bounds__(256) void k_xb(
        const float* __restrict__ x, unsigned short* __restrict__ xb, int N) {
    int gid = blockIdx.x * 256 + threadIdx.x;
    if (gid >= N * (KP / 8)) return;
    int row = gid / (KP / 8);
    int k0 = (gid % (KP / 8)) * 8;
    unsigned short v[8];
#pragma unroll
    for (int i = 0; i < 8; ++i) {
        int k = k0 + i;
        v[i] = (k < NF) ? f2bf(x[(size_t)row * NF + k]) : (unsigned short)0;
    }
    uint4 pk;
    pk.x = (unsigned)v[0] | ((unsigned)v[1] << 16);
    pk.y = (unsigned)v[2] | ((unsigned)v[3] << 16);
    pk.z = (unsigned)v[4] | ((unsigned)v[5] << 16);
    pk.w = (unsigned)v[6] | ((unsigned)v[7] << 16);
    *(uint4*)(xb + (size_t)row * KP + k0) = pk;
}

__global__ __launch_bounds__(256) void k_wbt(
        const float* __restrict__ W1, unsigned short* __restrict__ wbt) {
    int gid = blockIdx.x * 256 + threadIdx.x;
    if (gid >= NCOLS * (KP / 8)) return;
    int col = gid / (KP / 8);
    int k0 = (gid % (KP / 8)) * 8;
    int cc = col & 127;
    unsigned short v[8];
#pragma unroll
    for (int i = 0; i < 8; ++i) {
        int k = k0 + i;
        float f = 0.0f;
        if (k < NF) {
            if (col < 128)      f = W1[k * 128 + cc] - W1[42240 + k * 128 + cc];
            else if (col < 256) f = W1[21120 + k * 128 + cc];
            else                f = W1[42240 + k * 128 + cc];
        }
        v[i] = f2bf(f);
    }
    uint4 pk;
    pk.x = (unsigned)v[0] | ((unsigned)v[1] << 16);
    pk.y = (unsigned)v[2] | ((unsigned)v[3] << 16);
    pk.z = (unsigned)v[4] | ((unsigned)v[5] << 16);
    pk.w = (unsigned)v[6] | ((unsigned)v[7] << 16);
    *(uint4*)(wbt + (size_t)col * KP + k0) = pk;
}

// Wc2t[8][128] TRANSPOSED: row t (output col), col k (hidden).
__global__ __launch_bounds__(256) void k_wc2t(const float* __restrict__ W2,
                                              float* __restrict__ Wc2t) {
    int gid = blockIdx.x * 256 + threadIdx.x;
    if (gid >= 8 * 128) return;
    int t = gid >> 7;
    int k = gid & 127;
    float v = 0.0f;
    if (t < 2)      v = W2[k * 2 + t] - W2[512 + k * 2 + t];
    else if (t < 4) v = W2[256 + k * 2 + (t - 2)];
    else if (t < 6) v = W2[512 + k * 2 + (t - 4)];
    Wc2t[gid] = v;
}

// ---- GEMM1 via MFMA ------------------------------------------------------
// XCD-local panel swizzle: bid&7 = XCD; each XCD runs all 3 col-groups of
// its panels consecutively -> xb panel fetched once into that XCD's L2.
__global__ __launch_bounds__(256) void k_gemm1_mfma(
        const unsigned short* __restrict__ xb, const unsigned short* __restrict__ wbt,
        const float* __restrict__ dis,
        unsigned int* __restrict__ ub, unsigned int* __restrict__ sA,
        unsigned int* __restrict__ wb, int N, int P) {
    int xcd = blockIdx.x & 7;
    int wrk = blockIdx.x >> 3;
    int p = xcd + 8 * (wrk / 3);
    int g = wrk - 3 * (wrk / 3);
    if (p >= P) return;

    __shared__ unsigned short As[128][40];
    __shared__ unsigned short Bs[128][40];

    int tid = threadIdx.x;
    int w = tid >> 6;
    int lane = tid & 63;
    int l15 = lane & 15;
    int l16 = lane >> 4;
    int brow = p * 128;
    int gcol = g * 128;

    int sr = tid >> 1;
    int sk = (tid & 1) * 16;

    f32x4 acc[2][8] = {};

    for (int kc = 0; kc < 6; ++kc) {
        int k0 = kc * 32;
        uint4 va0 = {0, 0, 0, 0}, va1 = {0, 0, 0, 0};
        if (brow + sr < N) {
            const unsigned short* asrc = xb + (size_t)(brow + sr) * KP + k0 + sk;
            va0 = *(const uint4*)asrc;
            va1 = *(const uint4*)(asrc + 8);
        }
        const unsigned short* bsrc = wbt + (size_t)(gcol + sr) * KP + k0 + sk;
        uint4 vb0 = *(const uint4*)bsrc;
        uint4 vb1 = *(const uint4*)(bsrc + 8);
        __syncthreads();
        *(uint4*)&As[sr][sk] = va0;
        *(uint4*)&As[sr][sk + 8] = va1;
        *(uint4*)&Bs[sr][sk] = vb0;
        *(uint4*)&Bs[sr][sk + 8] = vb1;
        __syncthreads();

        bf16x8 a[2], b[8];
#pragma unroll
        for (int m = 0; m < 2; ++m)
            a[m] = *(const bf16x8*)&As[w * 32 + m * 16 + l15][l16 * 8];
#pragma unroll
        for (int n = 0; n < 8; ++n)
            b[n] = *(const bf16x8*)&Bs[n * 16 + l15][l16 * 8];
#pragma unroll
        for (int m = 0; m < 2; ++m)
#pragma unroll
            for (int n = 0; n < 8; ++n)
                acc[m][n] = __builtin_amdgcn_mfma_f32_16x16x32_bf16(
                    a[m], b[n], acc[m][n], 0, 0, 0);
    }

    unsigned int* dst = (g == 0) ? ub : (g == 1) ? sA : wb;
#pragma unroll
    for (int m = 0; m < 2; ++m) {
#pragma unroll
        for (int reg = 0; reg < 4; ++reg) {
            int row = brow + w * 32 + m * 16 + l16 * 4 + reg;
            if (row >= N) continue;
            float sc = (g == 0) ? 1.0f : dis[row];
#pragma unroll
            for (int n = 0; n < 4; ++n) {
                int c = n * 16 + l15;
                float lo = sc * acc[m][n][reg];
                float hi = sc * acc[m][n + 4][reg];
                dst[(size_t)row * 64 + c] =
                    (unsigned)f2bf(lo) | ((unsigned)f2bf(hi) << 16);
            }
        }
    }
}

// ---- 128-wide props: 4 rows/wave, 16 lanes/row, uint4 gathers, unroll-4 ---

// sb[r] = bf16( sA[r] - 2*dis[r]^2 * sum_e wb[col] )
__global__ __launch_bounds__(256) void k_prop_b2b(
        const int* __restrict__ off, const int* __restrict__ scol,
        const unsigned int* __restrict__ srcb, const unsigned int* __restrict__ addb,
        const float* __restrict__ dis, unsigned int* __restrict__ dstb, int N) {
    int wid = (blockIdx.x * 256 + threadIdx.x) >> 6;
    int lane = threadIdx.x & 63;
    int g = lane >> 4, q = lane & 15;
    int r = wid * 4 + g;
    if (r >= N) return;
    int e = off[r], end = off[r + 1];
    const uint4* src4 = (const uint4*)srcb;
    float a[8] = {}, b[8] = {};
    for (; e + 4 <= end; e += 4) {
        int c0 = scol[e], c1 = scol[e + 1], c2 = scol[e + 2], c3 = scol[e + 3];
        uint4 v0 = src4[(size_t)c0 * 16 + q];
        uint4 v1 = src4[(size_t)c1 * 16 + q];
        uint4 v2 = src4[(size_t)c2 * 16 + q];
        uint4 v3 = src4[(size_t)c3 * 16 + q];
        ACC8(a, v0);
        ACC8(b, v1);
        ACC8(a, v2);
        ACC8(b, v3);
    }
    for (; e < end; ++e) {
        int c0 = scol[e];
        uint4 v0 = src4[(size_t)c0 * 16 + q];
        ACC8(a, v0);
    }
    float d = dis[r];
    float m2 = -2.0f * d * d;
    uint4 ad = ((const uint4*)addb)[(size_t)r * 16 + q];
    unsigned adp[4] = {ad.x, ad.y, ad.z, ad.w};
    uint4 o;
    unsigned* op = (unsigned*)&o;
#pragma unroll
    for (int j = 0; j < 4; ++j) {
        float lo = bf2f_lo(adp[j]) + m2 * (a[2 * j] + b[2 * j]);
        float hi = bf2f_hi(adp[j]) + m2 * (a[2 * j + 1] + b[2 * j + 1]);
        op[j] = (unsigned)f2bf(lo) | ((unsigned)f2bf(hi) << 16);
    }
    ((uint4*)dstb)[(size_t)r * 16 + q] = o;
}

// Fused: h = relu(ub - dis*prop(sb) + b1) in registers, contracted with
// Wc2t (transposed LDS: Ws[t*128+c], bank = c%32 -> 2-way only, free).
__global__ __launch_bounds__(256) void k_prop_b2f_gemm2(
        const int* __restrict__ off, const int* __restrict__ scol,
        const unsigned int* __restrict__ srcb, const unsigned int* __restrict__ addb,
        const float* __restrict__ dis, const float* __restrict__ b1,
        const float* __restrict__ Wc2t, const float* __restrict__ b2,
        float* __restrict__ out, float* __restrict__ s2, float* __restrict__ w2,
        int N) {
    __shared__ float Ws[8 * 128];
    int tid = threadIdx.x;
    for (int idx = tid; idx < 8 * 128; idx += 256) Ws[idx] = Wc2t[idx];
    __syncthreads();

    int wid = (blockIdx.x * 256 + tid) >> 6;
    int lane = tid & 63;
    int g = lane >> 4, q = lane & 15;
    int r = wid * 4 + g;
    if (r >= N) return;

    float blo[4], bhi[4];
#pragma unroll
    for (int j = 0; j < 4; ++j) {
        blo[j] = b1[q * 4 + j];
        bhi[j] = b1[q * 4 + j + 64];
    }

    int e = off[r], end = off[r + 1];
    const uint4* src4 = (const uint4*)srcb;
    float a[8] = {}, b[8] = {};
    for (; e + 4 <= end; e += 4) {
        int c0 = scol[e], c1 = scol[e + 1], c2 = scol[e + 2], c3 = scol[e + 3];
        uint4 v0 = src4[(size_t)c0 * 16 + q];
        uint4 v1 = src4[(size_t)c1 * 16 + q];
        uint4 v2 = src4[(size_t)c2 * 16 + q];
        uint4 v3 = src4[(size_t)c3 * 16 + q];
        ACC8(a, v0);
        ACC8(b, v1);
        ACC8(a, v2);
        ACC8(b, v3);
    }
    for (; e < end; ++e) {
        int c0 = scol[e];
        uint4 v0 = src4[(size_t)c0 * 16 + q];
        ACC8(a, v0);
    }
    float m1 = -dis[r];
    uint4 ad = ((const uint4*)addb)[(size_t)r * 16 + q];
    unsigned adp[4] = {ad.x, ad.y, ad.z, ad.w};
    float acc[6] = {};
#pragma unroll
    for (int j = 0; j < 4; ++j) {
        int c = q * 4 + j;
        float lo = fmaxf(bf2f_lo(adp[j]) + m1 * (a[2 * j] + b[2 * j]) + blo[j], 0.0f);
        float hi = fmaxf(bf2f_hi(adp[j]) + m1 * (a[2 * j + 1] + b[2 * j + 1]) + bhi[j], 0.0f);
#pragma unroll
        for (int t = 0; t < 6; ++t)
            acc[t] += lo * Ws[t * 128 + c] + hi * Ws[t * 128 + c + 64];
    }
#pragma unroll
    for (int ofs = 8; ofs; ofs >>= 1) {
#pragma unroll
        for (int t = 0; t < 6; ++t)
            acc[t] += __shfl_xor(acc[t], ofs);
    }
    if (q == 0) {
        float d = dis[r];
        out[(size_t)r * 2 + 0] = acc[0] + b2[0];
        out[(size_t)r * 2 + 1] = acc[1] + b2[1];
        s2[(size_t)r * 2 + 0] = d * acc[2];
        s2[(size_t)r * 2 + 1] = d * acc[3];
        w2[(size_t)r * 2 + 0] = d * acc[4];
        w2[(size_t)r * 2 + 1] = d * acc[5];
    }
}

// CSR prop, 2-wide: dst[r] = add[r] + m * sum src[col], m = sq ? -2*dis^2 : -dis.
__global__ __launch_bounds__(256) void k_prop2_csr(
        const int* __restrict__ off, const int* __restrict__ scol,
        const float* __restrict__ src, const float* __restrict__ add,
        const float* __restrict__ dis, float* __restrict__ dst,
        int sq, int N) {
    int r = blockIdx.x * 256 + threadIdx.x;
    if (r >= N) return;
    int e0 = off[r], e1 = off[r + 1];
    float a0 = 0.0f, a1 = 0.0f, b0 = 0.0f, b1v = 0.0f;
    int e = e0;
    for (; e + 2 <= e1; e += 2) {
        int c0 = scol[e], c1 = scol[e + 1];
        float2 v0 = *(const float2*)(src + (size_t)c0 * 2);
        float2 v1 = *(const float2*)(src + (size_t)c1 * 2);
        a0 += v0.x; a1 += v0.y;
        b0 += v1.x; b1v += v1.y;
    }
    if (e < e1) {
        int c0 = scol[e];
        float2 v0 = *(const float2*)(src + (size_t)c0 * 2);
        a0 += v0.x; a1 += v0.y;
    }
    a0 += b0; a1 += b1v;
    float d = dis[r];
    float m = sq ? (-2.0f * d * d) : (-d);
    float2 ad = *(const float2*)(add + (size_t)r * 2);
    float2 o = {ad.x + m * a0, ad.y + m * a1};
    *(float2*)(dst + (size_t)r * 2) = o;
}

extern "C" void kernel_launch(void* const* d_in, const int* in_sizes, int n_in,
                              void* d_out, int out_size, void* d_ws, size_t ws_size,
                              hipStream_t stream) {
    const float* x   = (const float*)d_in[0];
    const int* eidx  = (const int*)d_in[1];
    const float* W1  = (const float*)d_in[2];
    const float* b1  = (const float*)d_in[3];
    const float* W2  = (const float*)d_in[4];
    const float* b2  = (const float*)d_in[5];
    float* out       = (float*)d_out;

    int N = in_sizes[0] / NF;
    int E = in_sizes[1] / 2;
    const int* erow = eidx;
    const int* ecol = eidx + E;
    int NBK = (N + BROWS - 1) >> BSH;

    char* p = (char*)d_ws;
    auto alloc = [&](size_t bytes) {
        char* q = p;
        p += (bytes + 255) & ~(size_t)255;
        return q;
    };
    unsigned int* ub = (unsigned int*)alloc((size_t)N * 64 * 4);
    unsigned int* sA = (unsigned int*)alloc((size_t)N * 64 * 4);
    unsigned int* wb = (unsigned int*)alloc((size_t)N * 64 * 4);
    unsigned int* sb = (unsigned int*)alloc((size_t)N * 64 * 4);
    unsigned short* xb  = (unsigned short*)alloc((size_t)N * KP * 2);
    unsigned short* wbt = (unsigned short*)alloc((size_t)NCOLS * KP * 2);
    float* dis  = (float*)alloc((size_t)N * 4);
    int* cnt    = (int*)alloc((size_t)N * 4);
    int* off    = (int*)alloc((size_t)(N + 1) * 4);
    int* bsum   = (int*)alloc((size_t)256 * 4);
    int* bcur   = (int*)alloc((size_t)NBK * NSUB * CPAD * 4);
    unsigned int* bkt = (unsigned int*)alloc((size_t)NBK * NSUB * BSUBCAP * 4);
    int* scol   = (int*)alloc((size_t)E * 4);
    float* Wc2t = (float*)alloc((size_t)8 * 128 * 4);
    float* s2   = (float*)alloc((size_t)N * 2 * 4);
    float* w2   = (float*)alloc((size_t)N * 2 * 4);

    hipMemsetAsync(bcur, 0, (size_t)NBK * NSUB * CPAD * 4, stream);

    int gN = (N + 255) / 256;
    int NB = (N + 1023) / 1024;

    // conversions
    k_xb<<<(N * (KP / 8) + 255) / 256, 256, 0, stream>>>(x, xb, N);
    k_wbt<<<(NCOLS * (KP / 8) + 255) / 256, 256, 0, stream>>>(W1, wbt);
    k_wc2t<<<4, 256, 0, stream>>>(W2, Wc2t);

    // CSR build (radix-partition bucket pass, XCD-local sub-buckets)
    int gT = (E + TILE - 1) / TILE;
    k_bucket<<<gT, 256, 0, stream>>>(erow, ecol, bcur, bkt, E);
    k_hist<<<NBK, 256, 0, stream>>>(bcur, bkt, cnt, dis, N);
    k_scan1<<<NB, 256, 0, stream>>>(cnt, off, bsum, N);
    k_scan2<<<1, 256, 0, stream>>>(bsum, NB);
    k_scan3<<<gN, 256, 0, stream>>>(off, bsum, N, E);
    k_emit<<<NBK, 256, 0, stream>>>(bcur, bkt, off, scol, N);

    // layer 1: MFMA GEMM with XCD-local panel swizzle
    int P = (N + 127) / 128;
    int wPerX = 3 * ((P + 7) / 8);
    k_gemm1_mfma<<<8 * wPerX, 256, 0, stream>>>(xb, wbt, dis, ub, sA, wb, N, P);

    int nw4 = (N + 3) / 4;
    int gP4 = (nw4 * 64 + 255) / 256;
    // sb = bf16( sA - 2*dis^2 * prop-sum(wb) )
    k_prop_b2b<<<gP4, 256, 0, stream>>>(off, scol, wb, sA, dis, sb, N);
    // fused: h = relu(ub - dis*prop-sum(sb) + b1); out/s2/w2 = h @ W2
    k_prop_b2f_gemm2<<<gP4, 256, 0, stream>>>(off, scol, sb, ub, dis, b1,
                                              Wc2t, b2, out, s2, w2, N);

    // layer 2 props (2-wide)
    k_prop2_csr<<<gN, 256, 0, stream>>>(off, scol, w2, s2, dis, s2, 1, N);
    k_prop2_csr<<<gN, 256, 0, stream>>>(off, scol, s2, out, dis, out, 0, N);
}

// Round 17
// 544.296 us; speedup vs baseline: 1.3930x; 1.0049x over previous
//
#include <hip/hip_runtime.h>
#include <hip/hip_bf16.h>
#include <stdint.h>

#define NF 165
#define NH 128
#define KP 192          // padded K for MFMA
#define NCOLS 384
#define BSH 8           // rows per bucket = 256
#define BROWS 256
#define BCAP 6144       // whole-bucket capacity for emit LDS buffer
#define NSUB 8          // sub-buckets per bucket (one per XCD)
#define BSUBCAP 768     // per-(bucket,xcd) capacity (mean 512, +11 sigma)
#define CPAD 16         // cursor padding: 16 ints = 64B line
#define TILE 8192       // edges per bucket-pass block
#define NBKMAX 1024     // padded bucket count for block scan

typedef __attribute__((ext_vector_type(8))) short bf16x8;
typedef __attribute__((ext_vector_type(4))) float f32x4;

// ---- bf16 helpers --------------------------------------------------------

__device__ __forceinline__ unsigned short f2bf(float f) {
    unsigned int u = __builtin_bit_cast(unsigned int, f);
    u = (u + 0x7FFFu + ((u >> 16) & 1u)) >> 16;   // RNE
    return (unsigned short)u;
}
__device__ __forceinline__ float bf2f_lo(unsigned int v) {
    return __builtin_bit_cast(float, v << 16);
}
__device__ __forceinline__ float bf2f_hi(unsigned int v) {
    return __builtin_bit_cast(float, v & 0xFFFF0000u);
}

// accumulate a uint4 of bf16 pairs into acc[8]
#define ACC8(acc, v)                                                   \
    {                                                                  \
        unsigned _vv[4] = {(v).x, (v).y, (v).z, (v).w};                \
        _Pragma("unroll") for (int _j = 0; _j < 4; ++_j) {             \
            acc[2 * _j] += bf2f_lo(_vv[_j]);                           \
            acc[2 * _j + 1] += bf2f_hi(_vv[_j]);                       \
        }                                                              \
    }

// ---- CSR build ----------------------------------------------------------

// Radix-partition bucket pass (r16): LDS histogram -> block scan -> one
// cursor reservation per touched (bucket, xcd) -> rank into LDS stage ->
// coalesced contiguous write-out.
__global__ __launch_bounds__(256) void k_bucket(
        const int* __restrict__ erow, const int* __restrict__ ecol,
        int* __restrict__ bcur, unsigned int* __restrict__ bkt, int E) {
    __shared__ int hist[NBKMAX];
    __shared__ int basex[NBKMAX];
    __shared__ int gbase[NBKMAX];
    __shared__ int cur[NBKMAX];
    __shared__ int scanbuf[256];
    __shared__ unsigned stage[TILE];
    __shared__ unsigned short bof[TILE];

    int t = threadIdx.x;
    int x = blockIdx.x & (NSUB - 1);
    int e0 = blockIdx.x * TILE;
    int cnt = E - e0;
    if (cnt > TILE) cnt = TILE;
    if (cnt <= 0) return;

    for (int i = t; i < NBKMAX; i += 256) { hist[i] = 0; cur[i] = 0; }
    __syncthreads();

    // Phase A: histogram
    for (int i = t; i < cnt; i += 256) {
        int r = __builtin_nontemporal_load(erow + e0 + i);
        atomicAdd(&hist[r >> BSH], 1);
    }
    __syncthreads();

    // Phase B: block exclusive scan (4 buckets/thread) + global reservation
    int b0 = 4 * t;
    int h0 = hist[b0], h1 = hist[b0 + 1], h2 = hist[b0 + 2], h3 = hist[b0 + 3];
    int tsum = h0 + h1 + h2 + h3;
    scanbuf[t] = tsum;
    __syncthreads();
#pragma unroll
    for (int ofs = 1; ofs < 256; ofs <<= 1) {
        int v = (t >= ofs) ? scanbuf[t - ofs] : 0;
        __syncthreads();
        scanbuf[t] += v;
        __syncthreads();
    }
    int excl = scanbuf[t] - tsum;
    basex[b0] = excl;
    basex[b0 + 1] = excl + h0;
    basex[b0 + 2] = excl + h0 + h1;
    basex[b0 + 3] = excl + h0 + h1 + h2;
    int hb[4] = {h0, h1, h2, h3};
#pragma unroll
    for (int j = 0; j < 4; ++j) {
        int b = b0 + j;
        if (hb[j] > 0)
            gbase[b] = atomicAdd(&bcur[(b * NSUB + x) * CPAD], hb[j]);
    }
    __syncthreads();

    // Phase C: rank edges into bucket-sorted LDS stage
    for (int i = t; i < cnt; i += 256) {
        int r = __builtin_nontemporal_load(erow + e0 + i);
        int c = __builtin_nontemporal_load(ecol + e0 + i);
        int b = r >> BSH;
        int rk = atomicAdd(&cur[b], 1);
        int pos = basex[b] + rk;
        stage[pos] = ((unsigned)(r & (BROWS - 1)) << 18) | (unsigned)c;
        bof[pos] = (unsigned short)b;
    }
    __syncthreads();

    // Phase D: coalesced write-out (contiguous run per bucket)
    for (int i = t; i < cnt; i += 256) {
        int b = bof[i];
        int slot = gbase[b] + (i - basex[b]);
        if (slot < BSUBCAP)
            bkt[(size_t)(b * NSUB + x) * BSUBCAP + slot] = stage[i];
    }
}

// Bucket-total exclusive scan (one block): boff[b] = global region start.
__global__ __launch_bounds__(256) void k_bscan(
        const int* __restrict__ bcur, int* __restrict__ boff,
        int* __restrict__ off, int NBK, int N, int E) {
    __shared__ int scanbuf[256];
    int t = threadIdx.x;
    int tot[4];
    int tsum = 0;
#pragma unroll
    for (int j = 0; j < 4; ++j) {
        int b = 4 * t + j;
        int s = 0;
        if (b < NBK) {
#pragma unroll
            for (int x = 0; x < NSUB; ++x) {
                int nb = bcur[(b * NSUB + x) * CPAD];
                if (nb > BSUBCAP) nb = BSUBCAP;
                s += nb;
            }
        }
        tot[j] = s;
        tsum += s;
    }
    scanbuf[t] = tsum;
    __syncthreads();
#pragma unroll
    for (int ofs = 1; ofs < 256; ofs <<= 1) {
        int v = (t >= ofs) ? scanbuf[t - ofs] : 0;
        __syncthreads();
        scanbuf[t] += v;
        __syncthreads();
    }
    int excl = scanbuf[t] - tsum;
#pragma unroll
    for (int j = 0; j < 4; ++j) {
        int b = 4 * t + j;
        if (b < NBK) boff[b] = excl;
        excl += tot[j];
    }
    if (t == 255) off[N] = E;
}

// Fused emit: stage bucket records once -> row histogram -> row scan ->
// write off + dis -> place into sorted colbuf -> coalesced scol write-out.
// Replaces k_hist + k_scan1/2/3 + old k_emit.
__global__ __launch_bounds__(256) void k_emit2(
        const int* __restrict__ bcur, const unsigned int* __restrict__ bkt,
        const int* __restrict__ boff, int* __restrict__ off,
        float* __restrict__ dis, int* __restrict__ scol, int N) {
    __shared__ unsigned stage[BCAP];
    __shared__ unsigned colbuf[BCAP];
    __shared__ int h[BROWS];
    __shared__ int rowex[BROWS];
    __shared__ int scanbuf[256];
    __shared__ int subofs[NSUB + 1];

    int b = blockIdx.x;
    int t = threadIdx.x;
    int base = b << BSH;
    int nrows = N - base;
    if (nrows > BROWS) nrows = BROWS;

    if (t == 0) {
        int run = 0;
#pragma unroll
        for (int x = 0; x < NSUB; ++x) {
            subofs[x] = run;
            int nb = bcur[(b * NSUB + x) * CPAD];
            if (nb > BSUBCAP) nb = BSUBCAP;
            run += nb;
        }
        subofs[NSUB] = run;
    }
    h[t] = 0;
    __syncthreads();
    int total = subofs[NSUB];

    // stage all records (coalesced per sub)
#pragma unroll
    for (int x = 0; x < NSUB; ++x) {
        int o = subofs[x];
        int n = subofs[x + 1] - o;
        const unsigned int* src = bkt + (size_t)(b * NSUB + x) * BSUBCAP;
        for (int i = t; i < n; i += 256)
            stage[o + i] = __builtin_nontemporal_load(src + i);
    }
    __syncthreads();

    // row histogram
    for (int i = t; i < total; i += 256)
        atomicAdd(&h[stage[i] >> 18], 1);
    __syncthreads();

    // scan 256 rows
    int hv = h[t];
    scanbuf[t] = hv;
    __syncthreads();
#pragma unroll
    for (int ofs = 1; ofs < 256; ofs <<= 1) {
        int v = (t >= ofs) ? scanbuf[t - ofs] : 0;
        __syncthreads();
        scanbuf[t] += v;
        __syncthreads();
    }
    int excl = scanbuf[t] - hv;
    rowex[t] = excl;
    if (t < nrows) {
        off[base + t] = boff[b] + excl;
        dis[base + t] = (hv > 0) ? rsqrtf((float)hv) : 0.0f;
    }
    h[t] = 0;   // reuse as placement cursor
    __syncthreads();

    // place into row-sorted colbuf
    for (int i = t; i < total; i += 256) {
        unsigned v = stage[i];
        int rl = v >> 18;
        int pos = rowex[rl] + atomicAdd(&h[rl], 1);
        colbuf[pos] = v & 0x3FFFFu;
    }
    __syncthreads();

    int gs = boff[b];
    for (int i = t; i < total; i += 256) scol[gs + i] = (int)colbuf[i];
}

// ---- conversions ---------------------------------------------------------

__global__ __launch_bounds__(256) void k_xb(
        const float* __restrict__ x, unsigned short* __restrict__ xb, int N) {
    int gid = blockIdx.x * 256 + threadIdx.x;
    if (gid >= N * (KP / 8)) return;
    int row = gid / (KP / 8);
    int k0 = (gid % (KP / 8)) * 8;
    unsigned short v[8];
#pragma unroll
    for (int i = 0; i < 8; ++i) {
        int k = k0 + i;
        v[i] = (k < NF) ? f2bf(x[(size_t)row * NF + k]) : (unsigned short)0;
    }
    uint4 pk;
    pk.x = (unsigned)v[0] | ((unsigned)v[1] << 16);
    pk.y = (unsigned)v[2] | ((unsigned)v[3] << 16);
    pk.z = (unsigned)v[4] | ((unsigned)v[5] << 16);
    pk.w = (unsigned)v[6] | ((unsigned)v[7] << 16);
    *(uint4*)(xb + (size_t)row * KP + k0) = pk;
}

__global__ __launch_bounds__(256) void k_wbt(
        const float* __restrict__ W1, unsigned short* __restrict__ wbt) {
    int gid = blockIdx.x * 256 + threadIdx.x;
    if (gid >= NCOLS * (KP / 8)) return;
    int col = gid / (KP / 8);
    int k0 = (gid % (KP / 8)) * 8;
    int cc = col & 127;
    unsigned short v[8];
#pragma unroll
    for (int i = 0; i < 8; ++i) {
        int k = k0 + i;
        float f = 0.0f;
        if (k < NF) {
            if (col < 128)      f = W1[k * 128 + cc] - W1[42240 + k * 128 + cc];
            else if (col < 256) f = W1[21120 + k * 128 + cc];
            else                f = W1[42240 + k * 128 + cc];
        }
        v[i] = f2bf(f);
    }
    uint4 pk;
    pk.x = (unsigned)v[0] | ((unsigned)v[1] << 16);
    pk.y = (unsigned)v[2] | ((unsigned)v[3] << 16);
    pk.z = (unsigned)v[4] | ((unsigned)v[5] << 16);
    pk.w = (unsigned)v[6] | ((unsigned)v[7] << 16);
    *(uint4*)(wbt + (size_t)col * KP + k0) = pk;
}

// Wc2t[8][128] TRANSPOSED: row t (output col), col k (hidden).
__global__ __launch_bounds__(256) void k_wc2t(const float* __restrict__ W2,
                                              float* __restrict__ Wc2t) {
    int gid = blockIdx.x * 256 + threadIdx.x;
    if (gid >= 8 * 128) return;
    int t = gid >> 7;
    int k = gid & 127;
    float v = 0.0f;
    if (t < 2)      v = W2[k * 2 + t] - W2[512 + k * 2 + t];
    else if (t < 4) v = W2[256 + k * 2 + (t - 2)];
    else if (t < 6) v = W2[512 + k * 2 + (t - 4)];
    Wc2t[gid] = v;
}

// ---- GEMM1 via MFMA ------------------------------------------------------
// XCD-local panel swizzle: bid&7 = XCD; each XCD runs all 3 col-groups of
// its panels consecutively -> xb panel fetched once into that XCD's L2.
__global__ __launch_bounds__(256) void k_gemm1_mfma(
        const unsigned short* __restrict__ xb, const unsigned short* __restrict__ wbt,
        const float* __restrict__ dis,
        unsigned int* __restrict__ ub, unsigned int* __restrict__ sA,
        unsigned int* __restrict__ wb, int N, int P) {
    int xcd = blockIdx.x & 7;
    int wrk = blockIdx.x >> 3;
    int p = xcd + 8 * (wrk / 3);
    int g = wrk - 3 * (wrk / 3);
    if (p >= P) return;

    __shared__ unsigned short As[128][40];
    __shared__ unsigned short Bs[128][40];

    int tid = threadIdx.x;
    int w = tid >> 6;
    int lane = tid & 63;
    int l15 = lane & 15;
    int l16 = lane >> 4;
    int brow = p * 128;
    int gcol = g * 128;

    int sr = tid >> 1;
    int sk = (tid & 1) * 16;

    f32x4 acc[2][8] = {};

    for (int kc = 0; kc < 6; ++kc) {
        int k0 = kc * 32;
        uint4 va0 = {0, 0, 0, 0}, va1 = {0, 0, 0, 0};
        if (brow + sr < N) {
            const unsigned short* asrc = xb + (size_t)(brow + sr) * KP + k0 + sk;
            va0 = *(const uint4*)asrc;
            va1 = *(const uint4*)(asrc + 8);
        }
        const unsigned short* bsrc = wbt + (size_t)(gcol + sr) * KP + k0 + sk;
        uint4 vb0 = *(const uint4*)bsrc;
        uint4 vb1 = *(const uint4*)(bsrc + 8);
        __syncthreads();
        *(uint4*)&As[sr][sk] = va0;
        *(uint4*)&As[sr][sk + 8] = va1;
        *(uint4*)&Bs[sr][sk] = vb0;
        *(uint4*)&Bs[sr][sk + 8] = vb1;
        __syncthreads();

        bf16x8 a[2], b[8];
#pragma unroll
        for (int m = 0; m < 2; ++m)
            a[m] = *(const bf16x8*)&As[w * 32 + m * 16 + l15][l16 * 8];
#pragma unroll
        for (int n = 0; n < 8; ++n)
            b[n] = *(const bf16x8*)&Bs[n * 16 + l15][l16 * 8];
#pragma unroll
        for (int m = 0; m < 2; ++m)
#pragma unroll
            for (int n = 0; n < 8; ++n)
                acc[m][n] = __builtin_amdgcn_mfma_f32_16x16x32_bf16(
                    a[m], b[n], acc[m][n], 0, 0, 0);
    }

    unsigned int* dst = (g == 0) ? ub : (g == 1) ? sA : wb;
#pragma unroll
    for (int m = 0; m < 2; ++m) {
#pragma unroll
        for (int reg = 0; reg < 4; ++reg) {
            int row = brow + w * 32 + m * 16 + l16 * 4 + reg;
            if (row >= N) continue;
            float sc = (g == 0) ? 1.0f : dis[row];
#pragma unroll
            for (int n = 0; n < 4; ++n) {
                int c = n * 16 + l15;
                float lo = sc * acc[m][n][reg];
                float hi = sc * acc[m][n + 4][reg];
                dst[(size_t)row * 64 + c] =
                    (unsigned)f2bf(lo) | ((unsigned)f2bf(hi) << 16);
            }
        }
    }
}

// ---- 128-wide props: 4 rows/wave, 16 lanes/row, uint4 gathers, unroll-4 ---

// sb[r] = bf16( sA[r] - 2*dis[r]^2 * sum_e wb[col] )
__global__ __launch_bounds__(256) void k_prop_b2b(
        const int* __restrict__ off, const int* __restrict__ scol,
        const unsigned int* __restrict__ srcb, const unsigned int* __restrict__ addb,
        const float* __restrict__ dis, unsigned int* __restrict__ dstb, int N) {
    int wid = (blockIdx.x * 256 + threadIdx.x) >> 6;
    int lane = threadIdx.x & 63;
    int g = lane >> 4, q = lane & 15;
    int r = wid * 4 + g;
    if (r >= N) return;
    int e = off[r], end = off[r + 1];
    const uint4* src4 = (const uint4*)srcb;
    float a[8] = {}, b[8] = {};
    for (; e + 4 <= end; e += 4) {
        int c0 = scol[e], c1 = scol[e + 1], c2 = scol[e + 2], c3 = scol[e + 3];
        uint4 v0 = src4[(size_t)c0 * 16 + q];
        uint4 v1 = src4[(size_t)c1 * 16 + q];
        uint4 v2 = src4[(size_t)c2 * 16 + q];
        uint4 v3 = src4[(size_t)c3 * 16 + q];
        ACC8(a, v0);
        ACC8(b, v1);
        ACC8(a, v2);
        ACC8(b, v3);
    }
    for (; e < end; ++e) {
        int c0 = scol[e];
        uint4 v0 = src4[(size_t)c0 * 16 + q];
        ACC8(a, v0);
    }
    float d = dis[r];
    float m2 = -2.0f * d * d;
    uint4 ad = ((const uint4*)addb)[(size_t)r * 16 + q];
    unsigned adp[4] = {ad.x, ad.y, ad.z, ad.w};
    uint4 o;
    unsigned* op = (unsigned*)&o;
#pragma unroll
    for (int j = 0; j < 4; ++j) {
        float lo = bf2f_lo(adp[j]) + m2 * (a[2 * j] + b[2 * j]);
        float hi = bf2f_hi(adp[j]) + m2 * (a[2 * j + 1] + b[2 * j + 1]);
        op[j] = (unsigned)f2bf(lo) | ((unsigned)f2bf(hi) << 16);
    }
    ((uint4*)dstb)[(size_t)r * 16 + q] = o;
}

// Fused: h = relu(ub - dis*prop(sb) + b1) in registers, contracted with
// Wc2t (transposed LDS: Ws[t*128+c], bank = c%32 -> 2-way only, free).
__global__ __launch_bounds__(256) void k_prop_b2f_gemm2(
        const int* __restrict__ off, const int* __restrict__ scol,
        const unsigned int* __restrict__ srcb, const unsigned int* __restrict__ addb,
        const float* __restrict__ dis, const float* __restrict__ b1,
        const float* __restrict__ Wc2t, const float* __restrict__ b2,
        float* __restrict__ out, float* __restrict__ s2, float* __restrict__ w2,
        int N) {
    __shared__ float Ws[8 * 128];
    int tid = threadIdx.x;
    for (int idx = tid; idx < 8 * 128; idx += 256) Ws[idx] = Wc2t[idx];
    __syncthreads();

    int wid = (blockIdx.x * 256 + tid) >> 6;
    int lane = tid & 63;
    int g = lane >> 4, q = lane & 15;
    int r = wid * 4 + g;
    if (r >= N) return;

    float blo[4], bhi[4];
#pragma unroll
    for (int j = 0; j < 4; ++j) {
        blo[j] = b1[q * 4 + j];
        bhi[j] = b1[q * 4 + j + 64];
    }

    int e = off[r], end = off[r + 1];
    const uint4* src4 = (const uint4*)srcb;
    float a[8] = {}, b[8] = {};
    for (; e + 4 <= end; e += 4) {
        int c0 = scol[e], c1 = scol[e + 1], c2 = scol[e + 2], c3 = scol[e + 3];
        uint4 v0 = src4[(size_t)c0 * 16 + q];
        uint4 v1 = src4[(size_t)c1 * 16 + q];
        uint4 v2 = src4[(size_t)c2 * 16 + q];
        uint4 v3 = src4[(size_t)c3 * 16 + q];
        ACC8(a, v0);
        ACC8(b, v1);
        ACC8(a, v2);
        ACC8(b, v3);
    }
    for (; e < end; ++e) {
        int c0 = scol[e];
        uint4 v0 = src4[(size_t)c0 * 16 + q];
        ACC8(a, v0);
    }
    float m1 = -dis[r];
    uint4 ad = ((const uint4*)addb)[(size_t)r * 16 + q];
    unsigned adp[4] = {ad.x, ad.y, ad.z, ad.w};
    float acc[6] = {};
#pragma unroll
    for (int j = 0; j < 4; ++j) {
        int c = q * 4 + j;
        float lo = fmaxf(bf2f_lo(adp[j]) + m1 * (a[2 * j] + b[2 * j]) + blo[j], 0.0f);
        float hi = fmaxf(bf2f_hi(adp[j]) + m1 * (a[2 * j + 1] + b[2 * j + 1]) + bhi[j], 0.0f);
#pragma unroll
        for (int t = 0; t < 6; ++t)
            acc[t] += lo * Ws[t * 128 + c] + hi * Ws[t * 128 + c + 64];
    }
#pragma unroll
    for (int ofs = 8; ofs; ofs >>= 1) {
#pragma unroll
        for (int t = 0; t < 6; ++t)
            acc[t] += __shfl_xor(acc[t], ofs);
    }
    if (q == 0) {
        float d = dis[r];
        out[(size_t)r * 2 + 0] = acc[0] + b2[0];
        out[(size_t)r * 2 + 1] = acc[1] + b2[1];
        s2[(size_t)r * 2 + 0] = d * acc[2];
        s2[(size_t)r * 2 + 1] = d * acc[3];
        w2[(size_t)r * 2 + 0] = d * acc[4];
        w2[(size_t)r * 2 + 1] = d * acc[5];
    }
}

// CSR prop, 2-wide: dst[r] = add[r] + m * sum src[col], m = sq ? -2*dis^2 : -dis.
__global__ __launch_bounds__(256) void k_prop2_csr(
        const int* __restrict__ off, const int* __restrict__ scol,
        const float* __restrict__ src, const float* __restrict__ add,
        const float* __restrict__ dis, float* __restrict__ dst,
        int sq, int N) {
    int r = blockIdx.x * 256 + threadIdx.x;
    if (r >= N) return;
    int e0 = off[r], e1 = off[r + 1];
    float a0 = 0.0f, a1 = 0.0f, b0 = 0.0f, b1v = 0.0f;
    int e = e0;
    for (; e + 2 <= e1; e += 2) {
        int c0 = scol[e], c1 = scol[e + 1];
        float2 v0 = *(const float2*)(src + (size_t)c0 * 2);
        float2 v1 = *(const float2*)(src + (size_t)c1 * 2);
        a0 += v0.x; a1 += v0.y;
        b0 += v1.x; b1v += v1.y;
    }
    if (e < e1) {
        int c0 = scol[e];
        float2 v0 = *(const float2*)(src + (size_t)c0 * 2);
        a0 += v0.x; a1 += v0.y;
    }
    a0 += b0; a1 += b1v;
    float d = dis[r];
    float m = sq ? (-2.0f * d * d) : (-d);
    float2 ad = *(const float2*)(add + (size_t)r * 2);
    float2 o = {ad.x + m * a0, ad.y + m * a1};
    *(float2*)(dst + (size_t)r * 2) = o;
}

extern "C" void kernel_launch(void* const* d_in, const int* in_sizes, int n_in,
                              void* d_out, int out_size, void* d_ws, size_t ws_size,
                              hipStream_t stream) {
    const float* x   = (const float*)d_in[0];
    const int* eidx  = (const int*)d_in[1];
    const float* W1  = (const float*)d_in[2];
    const float* b1  = (const float*)d_in[3];
    const float* W2  = (const float*)d_in[4];
    const float* b2  = (const float*)d_in[5];
    float* out       = (float*)d_out;

    int N = in_sizes[0] / NF;
    int E = in_sizes[1] / 2;
    const int* erow = eidx;
    const int* ecol = eidx + E;
    int NBK = (N + BROWS - 1) >> BSH;

    char* p = (char*)d_ws;
    auto alloc = [&](size_t bytes) {
        char* q = p;
        p += (bytes + 255) & ~(size_t)255;
        return q;
    };
    unsigned int* ub = (unsigned int*)alloc((size_t)N * 64 * 4);
    unsigned int* sA = (unsigned int*)alloc((size_t)N * 64 * 4);
    unsigned int* wb = (unsigned int*)alloc((size_t)N * 64 * 4);
    unsigned int* sb = (unsigned int*)alloc((size_t)N * 64 * 4);
    unsigned short* xb  = (unsigned short*)alloc((size_t)N * KP * 2);
    unsigned short* wbt = (unsigned short*)alloc((size_t)NCOLS * KP * 2);
    float* dis  = (float*)alloc((size_t)N * 4);
    int* off    = (int*)alloc((size_t)(N + 1) * 4);
    int* boff   = (int*)alloc((size_t)(NBK + 1) * 4);
    int* bcur   = (int*)alloc((size_t)NBK * NSUB * CPAD * 4);
    unsigned int* bkt = (unsigned int*)alloc((size_t)NBK * NSUB * BSUBCAP * 4);
    int* scol   = (int*)alloc((size_t)E * 4);
    float* Wc2t = (float*)alloc((size_t)8 * 128 * 4);
    float* s2   = (float*)alloc((size_t)N * 2 * 4);
    float* w2   = (float*)alloc((size_t)N * 2 * 4);

    hipMemsetAsync(bcur, 0, (size_t)NBK * NSUB * CPAD * 4, stream);

    int gN = (N + 255) / 256;

    // conversions
    k_xb<<<(N * (KP / 8) + 255) / 256, 256, 0, stream>>>(x, xb, N);
    k_wbt<<<(NCOLS * (KP / 8) + 255) / 256, 256, 0, stream>>>(W1, wbt);
    k_wc2t<<<4, 256, 0, stream>>>(W2, Wc2t);

    // CSR build (radix-partition bucket pass + fused emit)
    int gT = (E + TILE - 1) / TILE;
    k_bucket<<<gT, 256, 0, stream>>>(erow, ecol, bcur, bkt, E);
    k_bscan<<<1, 256, 0, stream>>>(bcur, boff, off, NBK, N, E);
    k_emit2<<<NBK, 256, 0, stream>>>(bcur, bkt, boff, off, dis, scol, N);

    // layer 1: MFMA GEMM with XCD-local panel swizzle
    int P = (N + 127) / 128;
    int wPerX = 3 * ((P + 7) / 8);
    k_gemm1_mfma<<<8 * wPerX, 256, 0, stream>>>(xb, wbt, dis, ub, sA, wb, N, P);

    int nw4 = (N + 3) / 4;
    int gP4 = (nw4 * 64 + 255) / 256;
    // sb = bf16( sA - 2*dis^2 * prop-sum(wb) )
    k_prop_b2b<<<gP4, 256, 0, stream>>>(off, scol, wb, sA, dis, sb, N);
    // fused: h = relu(ub - dis*prop-sum(sb) + b1); out/s2/w2 = h @ W2
    k_prop_b2f_gemm2<<<gP4, 256, 0, stream>>>(off, scol, sb, ub, dis, b1,
                                              Wc2t, b2, out, s2, w2, N);

    // layer 2 props (2-wide)
    k_prop2_csr<<<gN, 256, 0, stream>>>(off, scol, w2, s2, dis, s2, 1, N);
    k_prop2_csr<<<gN, 256, 0, stream>>>(off, scol, s2, out, dis, out, 0, N);
}

// Round 18
// 508.689 us; speedup vs baseline: 1.4905x; 1.0700x over previous
//
#include <hip/hip_runtime.h>
#include <hip/hip_bf16.h>
#include <stdint.h>

#define NF 165
#define NH 128
#define KP 192          // padded K for MFMA
#define NCOLS 384
#define BSH 8           // rows per bucket = 256
#define BROWS 256
#define BCAP 6144       // whole-bucket capacity for emit LDS buffer
#define NSUB 8          // sub-buckets per bucket (one per XCD)
#define BSUBCAP 768     // per-(bucket,xcd) capacity (mean 512, +11 sigma)
#define CPAD 16         // cursor padding: 16 ints = 64B line
#define TILE 8192       // edges per bucket-pass block
#define NBKMAX 1024     // padded bucket count for block scan

typedef __attribute__((ext_vector_type(8))) short bf16x8;
typedef __attribute__((ext_vector_type(4))) float f32x4;

// ---- bf16 helpers --------------------------------------------------------

__device__ __forceinline__ unsigned short f2bf(float f) {
    unsigned int u = __builtin_bit_cast(unsigned int, f);
    u = (u + 0x7FFFu + ((u >> 16) & 1u)) >> 16;   // RNE
    return (unsigned short)u;
}
__device__ __forceinline__ float bf2f_lo(unsigned int v) {
    return __builtin_bit_cast(float, v << 16);
}
__device__ __forceinline__ float bf2f_hi(unsigned int v) {
    return __builtin_bit_cast(float, v & 0xFFFF0000u);
}

// accumulate a uint4 of bf16 pairs into acc[8]
#define ACC8(acc, v)                                                   \
    {                                                                  \
        unsigned _vv[4] = {(v).x, (v).y, (v).z, (v).w};                \
        _Pragma("unroll") for (int _j = 0; _j < 4; ++_j) {             \
            acc[2 * _j] += bf2f_lo(_vv[_j]);                           \
            acc[2 * _j + 1] += bf2f_hi(_vv[_j]);                       \
        }                                                              \
    }

// ---- CSR build ----------------------------------------------------------

// Radix-partition bucket pass: LDS histogram -> block scan -> one cursor
// reservation per touched (bucket, xcd) -> rank into LDS stage -> coalesced
// contiguous write-out.
__global__ __launch_bounds__(256) void k_bucket(
        const int* __restrict__ erow, const int* __restrict__ ecol,
        int* __restrict__ bcur, unsigned int* __restrict__ bkt, int E) {
    __shared__ int hist[NBKMAX];
    __shared__ int basex[NBKMAX];
    __shared__ int gbase[NBKMAX];
    __shared__ int cur[NBKMAX];
    __shared__ int scanbuf[256];
    __shared__ unsigned stage[TILE];
    __shared__ unsigned short bof[TILE];

    int t = threadIdx.x;
    int x = blockIdx.x & (NSUB - 1);
    int e0 = blockIdx.x * TILE;
    int cnt = E - e0;
    if (cnt > TILE) cnt = TILE;
    if (cnt <= 0) return;

    for (int i = t; i < NBKMAX; i += 256) { hist[i] = 0; cur[i] = 0; }
    __syncthreads();

    // Phase A: histogram
    for (int i = t; i < cnt; i += 256) {
        int r = __builtin_nontemporal_load(erow + e0 + i);
        atomicAdd(&hist[r >> BSH], 1);
    }
    __syncthreads();

    // Phase B: block exclusive scan (4 buckets/thread) + global reservation
    int b0 = 4 * t;
    int h0 = hist[b0], h1 = hist[b0 + 1], h2 = hist[b0 + 2], h3 = hist[b0 + 3];
    int tsum = h0 + h1 + h2 + h3;
    scanbuf[t] = tsum;
    __syncthreads();
#pragma unroll
    for (int ofs = 1; ofs < 256; ofs <<= 1) {
        int v = (t >= ofs) ? scanbuf[t - ofs] : 0;
        __syncthreads();
        scanbuf[t] += v;
        __syncthreads();
    }
    int excl = scanbuf[t] - tsum;
    basex[b0] = excl;
    basex[b0 + 1] = excl + h0;
    basex[b0 + 2] = excl + h0 + h1;
    basex[b0 + 3] = excl + h0 + h1 + h2;
    int hb[4] = {h0, h1, h2, h3};
#pragma unroll
    for (int j = 0; j < 4; ++j) {
        int b = b0 + j;
        if (hb[j] > 0)
            gbase[b] = atomicAdd(&bcur[(b * NSUB + x) * CPAD], hb[j]);
    }
    __syncthreads();

    // Phase C: rank edges into bucket-sorted LDS stage
    for (int i = t; i < cnt; i += 256) {
        int r = __builtin_nontemporal_load(erow + e0 + i);
        int c = __builtin_nontemporal_load(ecol + e0 + i);
        int b = r >> BSH;
        int rk = atomicAdd(&cur[b], 1);
        int pos = basex[b] + rk;
        stage[pos] = ((unsigned)(r & (BROWS - 1)) << 18) | (unsigned)c;
        bof[pos] = (unsigned short)b;
    }
    __syncthreads();

    // Phase D: coalesced write-out (contiguous run per bucket)
    for (int i = t; i < cnt; i += 256) {
        int b = bof[i];
        int slot = gbase[b] + (i - basex[b]);
        if (slot < BSUBCAP)
            bkt[(size_t)(b * NSUB + x) * BSUBCAP + slot] = stage[i];
    }
}

// Bucket-total exclusive scan (one block): boff[b] = global region start.
__global__ __launch_bounds__(256) void k_bscan(
        const int* __restrict__ bcur, int* __restrict__ boff,
        int* __restrict__ off, int NBK, int N, int E) {
    __shared__ int scanbuf[256];
    int t = threadIdx.x;
    int tot[4];
    int tsum = 0;
#pragma unroll
    for (int j = 0; j < 4; ++j) {
        int b = 4 * t + j;
        int s = 0;
        if (b < NBK) {
#pragma unroll
            for (int x = 0; x < NSUB; ++x) {
                int nb = bcur[(b * NSUB + x) * CPAD];
                if (nb > BSUBCAP) nb = BSUBCAP;
                s += nb;
            }
        }
        tot[j] = s;
        tsum += s;
    }
    scanbuf[t] = tsum;
    __syncthreads();
#pragma unroll
    for (int ofs = 1; ofs < 256; ofs <<= 1) {
        int v = (t >= ofs) ? scanbuf[t - ofs] : 0;
        __syncthreads();
        scanbuf[t] += v;
        __syncthreads();
    }
    int excl = scanbuf[t] - tsum;
#pragma unroll
    for (int j = 0; j < 4; ++j) {
        int b = 4 * t + j;
        if (b < NBK) boff[b] = excl;
        excl += tot[j];
    }
    if (t == 255) off[N] = E;
}

// Fused emit: stage bucket records once -> row histogram -> row scan ->
// write off + dis -> place into sorted colbuf -> coalesced scol write-out.
__global__ __launch_bounds__(256) void k_emit2(
        const int* __restrict__ bcur, const unsigned int* __restrict__ bkt,
        const int* __restrict__ boff, int* __restrict__ off,
        float* __restrict__ dis, int* __restrict__ scol, int N) {
    __shared__ unsigned stage[BCAP];
    __shared__ unsigned colbuf[BCAP];
    __shared__ int h[BROWS];
    __shared__ int rowex[BROWS];
    __shared__ int scanbuf[256];
    __shared__ int subofs[NSUB + 1];

    int b = blockIdx.x;
    int t = threadIdx.x;
    int base = b << BSH;
    int nrows = N - base;
    if (nrows > BROWS) nrows = BROWS;

    if (t == 0) {
        int run = 0;
#pragma unroll
        for (int x = 0; x < NSUB; ++x) {
            subofs[x] = run;
            int nb = bcur[(b * NSUB + x) * CPAD];
            if (nb > BSUBCAP) nb = BSUBCAP;
            run += nb;
        }
        subofs[NSUB] = run;
    }
    h[t] = 0;
    __syncthreads();
    int total = subofs[NSUB];

#pragma unroll
    for (int x = 0; x < NSUB; ++x) {
        int o = subofs[x];
        int n = subofs[x + 1] - o;
        const unsigned int* src = bkt + (size_t)(b * NSUB + x) * BSUBCAP;
        for (int i = t; i < n; i += 256)
            stage[o + i] = __builtin_nontemporal_load(src + i);
    }
    __syncthreads();

    for (int i = t; i < total; i += 256)
        atomicAdd(&h[stage[i] >> 18], 1);
    __syncthreads();

    int hv = h[t];
    scanbuf[t] = hv;
    __syncthreads();
#pragma unroll
    for (int ofs = 1; ofs < 256; ofs <<= 1) {
        int v = (t >= ofs) ? scanbuf[t - ofs] : 0;
        __syncthreads();
        scanbuf[t] += v;
        __syncthreads();
    }
    int excl = scanbuf[t] - hv;
    rowex[t] = excl;
    if (t < nrows) {
        off[base + t] = boff[b] + excl;
        dis[base + t] = (hv > 0) ? rsqrtf((float)hv) : 0.0f;
    }
    h[t] = 0;
    __syncthreads();

    for (int i = t; i < total; i += 256) {
        unsigned v = stage[i];
        int rl = v >> 18;
        int pos = rowex[rl] + atomicAdd(&h[rl], 1);
        colbuf[pos] = v & 0x3FFFFu;
    }
    __syncthreads();

    int gs = boff[b];
    for (int i = t; i < total; i += 256) scol[gs + i] = (int)colbuf[i];
}

// ---- weight conversions ---------------------------------------------------

__global__ __launch_bounds__(256) void k_wbt(
        const float* __restrict__ W1, unsigned short* __restrict__ wbt) {
    int gid = blockIdx.x * 256 + threadIdx.x;
    if (gid >= NCOLS * (KP / 8)) return;
    int col = gid / (KP / 8);
    int k0 = (gid % (KP / 8)) * 8;
    int cc = col & 127;
    unsigned short v[8];
#pragma unroll
    for (int i = 0; i < 8; ++i) {
        int k = k0 + i;
        float f = 0.0f;
        if (k < NF) {
            if (col < 128)      f = W1[k * 128 + cc] - W1[42240 + k * 128 + cc];
            else if (col < 256) f = W1[21120 + k * 128 + cc];
            else                f = W1[42240 + k * 128 + cc];
        }
        v[i] = f2bf(f);
    }
    uint4 pk;
    pk.x = (unsigned)v[0] | ((unsigned)v[1] << 16);
    pk.y = (unsigned)v[2] | ((unsigned)v[3] << 16);
    pk.z = (unsigned)v[4] | ((unsigned)v[5] << 16);
    pk.w = (unsigned)v[6] | ((unsigned)v[7] << 16);
    *(uint4*)(wbt + (size_t)col * KP + k0) = pk;
}

// Wc2t[8][128] TRANSPOSED: row t (output col), col k (hidden).
__global__ __launch_bounds__(256) void k_wc2t(const float* __restrict__ W2,
                                              float* __restrict__ Wc2t) {
    int gid = blockIdx.x * 256 + threadIdx.x;
    if (gid >= 8 * 128) return;
    int t = gid >> 7;
    int k = gid & 127;
    float v = 0.0f;
    if (t < 2)      v = W2[k * 2 + t] - W2[512 + k * 2 + t];
    else if (t < 4) v = W2[256 + k * 2 + (t - 2)];
    else if (t < 6) v = W2[512 + k * 2 + (t - 4)];
    Wc2t[gid] = v;
}

// ---- GEMM1 via MFMA ------------------------------------------------------
// Reads x (f32) directly; converts to bf16 in A-staging (k_xb pass deleted).
// XCD-local panel swizzle: bid&7 = XCD; all 3 col-groups of a panel run on
// one XCD -> x panel fetched once into that XCD's L2.
__global__ __launch_bounds__(256) void k_gemm1_mfma(
        const float* __restrict__ x, const unsigned short* __restrict__ wbt,
        const float* __restrict__ dis,
        unsigned int* __restrict__ ub, unsigned int* __restrict__ sA,
        unsigned int* __restrict__ wb, int N, int P) {
    int xcd = blockIdx.x & 7;
    int wrk = blockIdx.x >> 3;
    int p = xcd + 8 * (wrk / 3);
    int g = wrk - 3 * (wrk / 3);
    if (p >= P) return;

    __shared__ unsigned short As[128][40];
    __shared__ unsigned short Bs[128][40];

    int tid = threadIdx.x;
    int w = tid >> 6;
    int lane = tid & 63;
    int l15 = lane & 15;
    int l16 = lane >> 4;
    int brow = p * 128;
    int gcol = g * 128;

    int sr = tid >> 1;
    int sk = (tid & 1) * 16;

    f32x4 acc[2][8] = {};

    for (int kc = 0; kc < 6; ++kc) {
        int k0 = kc * 32;
        unsigned short av[16];
        int row = brow + sr;
        if (row < N) {
            const float* asrc = x + (size_t)row * NF + k0 + sk;
            if (kc < 5) {
#pragma unroll
                for (int i = 0; i < 16; ++i) av[i] = f2bf(asrc[i]);
            } else {
#pragma unroll
                for (int i = 0; i < 16; ++i) {
                    int k = k0 + sk + i;
                    av[i] = (k < NF) ? f2bf(asrc[i]) : (unsigned short)0;
                }
            }
        } else {
#pragma unroll
            for (int i = 0; i < 16; ++i) av[i] = 0;
        }
        const unsigned short* bsrc = wbt + (size_t)(gcol + sr) * KP + k0 + sk;
        uint4 vb0 = *(const uint4*)bsrc;
        uint4 vb1 = *(const uint4*)(bsrc + 8);

        uint4 pa0, pa1;
        pa0.x = (unsigned)av[0] | ((unsigned)av[1] << 16);
        pa0.y = (unsigned)av[2] | ((unsigned)av[3] << 16);
        pa0.z = (unsigned)av[4] | ((unsigned)av[5] << 16);
        pa0.w = (unsigned)av[6] | ((unsigned)av[7] << 16);
        pa1.x = (unsigned)av[8] | ((unsigned)av[9] << 16);
        pa1.y = (unsigned)av[10] | ((unsigned)av[11] << 16);
        pa1.z = (unsigned)av[12] | ((unsigned)av[13] << 16);
        pa1.w = (unsigned)av[14] | ((unsigned)av[15] << 16);

        __syncthreads();
        *(uint4*)&As[sr][sk] = pa0;
        *(uint4*)&As[sr][sk + 8] = pa1;
        *(uint4*)&Bs[sr][sk] = vb0;
        *(uint4*)&Bs[sr][sk + 8] = vb1;
        __syncthreads();

        bf16x8 a[2], b[8];
#pragma unroll
        for (int m = 0; m < 2; ++m)
            a[m] = *(const bf16x8*)&As[w * 32 + m * 16 + l15][l16 * 8];
#pragma unroll
        for (int n = 0; n < 8; ++n)
            b[n] = *(const bf16x8*)&Bs[n * 16 + l15][l16 * 8];
#pragma unroll
        for (int m = 0; m < 2; ++m)
#pragma unroll
            for (int n = 0; n < 8; ++n)
                acc[m][n] = __builtin_amdgcn_mfma_f32_16x16x32_bf16(
                    a[m], b[n], acc[m][n], 0, 0, 0);
    }

    unsigned int* dst = (g == 0) ? ub : (g == 1) ? sA : wb;
#pragma unroll
    for (int m = 0; m < 2; ++m) {
#pragma unroll
        for (int reg = 0; reg < 4; ++reg) {
            int row = brow + w * 32 + m * 16 + l16 * 4 + reg;
            if (row >= N) continue;
            float sc = (g == 0) ? 1.0f : dis[row];
#pragma unroll
            for (int n = 0; n < 4; ++n) {
                int c = n * 16 + l15;
                float lo = sc * acc[m][n][reg];
                float hi = sc * acc[m][n + 4][reg];
                dst[(size_t)row * 64 + c] =
                    (unsigned)f2bf(lo) | ((unsigned)f2bf(hi) << 16);
            }
        }
    }
}

// ---- 128-wide props: 4 rows/wave, 16 lanes/row, uint4 gathers, unroll-4 ---

// sb[r] = bf16( sA[r] - 2*dis[r]^2 * sum_e wb[col] )
__global__ __launch_bounds__(256) void k_prop_b2b(
        const int* __restrict__ off, const int* __restrict__ scol,
        const unsigned int* __restrict__ srcb, const unsigned int* __restrict__ addb,
        const float* __restrict__ dis, unsigned int* __restrict__ dstb, int N) {
    int wid = (blockIdx.x * 256 + threadIdx.x) >> 6;
    int lane = threadIdx.x & 63;
    int g = lane >> 4, q = lane & 15;
    int r = wid * 4 + g;
    if (r >= N) return;
    int e = off[r], end = off[r + 1];
    const uint4* src4 = (const uint4*)srcb;
    float a[8] = {}, b[8] = {};
    for (; e + 4 <= end; e += 4) {
        int c0 = scol[e], c1 = scol[e + 1], c2 = scol[e + 2], c3 = scol[e + 3];
        uint4 v0 = src4[(size_t)c0 * 16 + q];
        uint4 v1 = src4[(size_t)c1 * 16 + q];
        uint4 v2 = src4[(size_t)c2 * 16 + q];
        uint4 v3 = src4[(size_t)c3 * 16 + q];
        ACC8(a, v0);
        ACC8(b, v1);
        ACC8(a, v2);
        ACC8(b, v3);
    }
    for (; e < end; ++e) {
        int c0 = scol[e];
        uint4 v0 = src4[(size_t)c0 * 16 + q];
        ACC8(a, v0);
    }
    float d = dis[r];
    float m2 = -2.0f * d * d;
    uint4 ad = ((const uint4*)addb)[(size_t)r * 16 + q];
    unsigned adp[4] = {ad.x, ad.y, ad.z, ad.w};
    uint4 o;
    unsigned* op = (unsigned*)&o;
#pragma unroll
    for (int j = 0; j < 4; ++j) {
        float lo = bf2f_lo(adp[j]) + m2 * (a[2 * j] + b[2 * j]);
        float hi = bf2f_hi(adp[j]) + m2 * (a[2 * j + 1] + b[2 * j + 1]);
        op[j] = (unsigned)f2bf(lo) | ((unsigned)f2bf(hi) << 16);
    }
    ((uint4*)dstb)[(size_t)r * 16 + q] = o;
}

// Fused: h = relu(ub - dis*prop(sb) + b1) in registers, contracted with
// Wc2t (transposed LDS: Ws[t*128+c], bank = c%32 -> 2-way only, free).
__global__ __launch_bounds__(256) void k_prop_b2f_gemm2(
        const int* __restrict__ off, const int* __restrict__ scol,
        const unsigned int* __restrict__ srcb, const unsigned int* __restrict__ addb,
        const float* __restrict__ dis, const float* __restrict__ b1,
        const float* __restrict__ Wc2t, const float* __restrict__ b2,
        float* __restrict__ out, float* __restrict__ s2, float* __restrict__ w2,
        int N) {
    __shared__ float Ws[8 * 128];
    int tid = threadIdx.x;
    for (int idx = tid; idx < 8 * 128; idx += 256) Ws[idx] = Wc2t[idx];
    __syncthreads();

    int wid = (blockIdx.x * 256 + tid) >> 6;
    int lane = tid & 63;
    int g = lane >> 4, q = lane & 15;
    int r = wid * 4 + g;
    if (r >= N) return;

    float blo[4], bhi[4];
#pragma unroll
    for (int j = 0; j < 4; ++j) {
        blo[j] = b1[q * 4 + j];
        bhi[j] = b1[q * 4 + j + 64];
    }

    int e = off[r], end = off[r + 1];
    const uint4* src4 = (const uint4*)srcb;
    float a[8] = {}, b[8] = {};
    for (; e + 4 <= end; e += 4) {
        int c0 = scol[e], c1 = scol[e + 1], c2 = scol[e + 2], c3 = scol[e + 3];
        uint4 v0 = src4[(size_t)c0 * 16 + q];
        uint4 v1 = src4[(size_t)c1 * 16 + q];
        uint4 v2 = src4[(size_t)c2 * 16 + q];
        uint4 v3 = src4[(size_t)c3 * 16 + q];
        ACC8(a, v0);
        ACC8(b, v1);
        ACC8(a, v2);
        ACC8(b, v3);
    }
    for (; e < end; ++e) {
        int c0 = scol[e];
        uint4 v0 = src4[(size_t)c0 * 16 + q];
        ACC8(a, v0);
    }
    float m1 = -dis[r];
    uint4 ad = ((const uint4*)addb)[(size_t)r * 16 + q];
    unsigned adp[4] = {ad.x, ad.y, ad.z, ad.w};
    float acc[6] = {};
#pragma unroll
    for (int j = 0; j < 4; ++j) {
        int c = q * 4 + j;
        float lo = fmaxf(bf2f_lo(adp[j]) + m1 * (a[2 * j] + b[2 * j]) + blo[j], 0.0f);
        float hi = fmaxf(bf2f_hi(adp[j]) + m1 * (a[2 * j + 1] + b[2 * j + 1]) + bhi[j], 0.0f);
#pragma unroll
        for (int t = 0; t < 6; ++t)
            acc[t] += lo * Ws[t * 128 + c] + hi * Ws[t * 128 + c + 64];
    }
#pragma unroll
    for (int ofs = 8; ofs; ofs >>= 1) {
#pragma unroll
        for (int t = 0; t < 6; ++t)
            acc[t] += __shfl_xor(acc[t], ofs);
    }
    if (q == 0) {
        float d = dis[r];
        out[(size_t)r * 2 + 0] = acc[0] + b2[0];
        out[(size_t)r * 2 + 1] = acc[1] + b2[1];
        s2[(size_t)r * 2 + 0] = d * acc[2];
        s2[(size_t)r * 2 + 1] = d * acc[3];
        w2[(size_t)r * 2 + 0] = d * acc[4];
        w2[(size_t)r * 2 + 1] = d * acc[5];
    }
}

// CSR prop, 2-wide: dst[r] = add[r] + m * sum src[col], m = sq ? -2*dis^2 : -dis.
__global__ __launch_bounds__(256) void k_prop2_csr(
        const int* __restrict__ off, const int* __restrict__ scol,
        const float* __restrict__ src, const float* __restrict__ add,
        const float* __restrict__ dis, float* __restrict__ dst,
        int sq, int N) {
    int r = blockIdx.x * 256 + threadIdx.x;
    if (r >= N) return;
    int e0 = off[r], e1 = off[r + 1];
    float a0 = 0.0f, a1 = 0.0f, b0 = 0.0f, b1v = 0.0f;
    int e = e0;
    for (; e + 2 <= e1; e += 2) {
        int c0 = scol[e], c1 = scol[e + 1];
        float2 v0 = *(const float2*)(src + (size_t)c0 * 2);
        float2 v1 = *(const float2*)(src + (size_t)c1 * 2);
        a0 += v0.x; a1 += v0.y;
        b0 += v1.x; b1v += v1.y;
    }
    if (e < e1) {
        int c0 = scol[e];
        float2 v0 = *(const float2*)(src + (size_t)c0 * 2);
        a0 += v0.x; a1 += v0.y;
    }
    a0 += b0; a1 += b1v;
    float d = dis[r];
    float m = sq ? (-2.0f * d * d) : (-d);
    float2 ad = *(const float2*)(add + (size_t)r * 2);
    float2 o = {ad.x + m * a0, ad.y + m * a1};
    *(float2*)(dst + (size_t)r * 2) = o;
}

extern "C" void kernel_launch(void* const* d_in, const int* in_sizes, int n_in,
                              void* d_out, int out_size, void* d_ws, size_t ws_size,
                              hipStream_t stream) {
    const float* x   = (const float*)d_in[0];
    const int* eidx  = (const int*)d_in[1];
    const float* W1  = (const float*)d_in[2];
    const float* b1  = (const float*)d_in[3];
    const float* W2  = (const float*)d_in[4];
    const float* b2  = (const float*)d_in[5];
    float* out       = (float*)d_out;

    int N = in_sizes[0] / NF;
    int E = in_sizes[1] / 2;
    const int* erow = eidx;
    const int* ecol = eidx + E;
    int NBK = (N + BROWS - 1) >> BSH;

    char* p = (char*)d_ws;
    auto alloc = [&](size_t bytes) {
        char* q = p;
        p += (bytes + 255) & ~(size_t)255;
        return q;
    };
    unsigned int* ub = (unsigned int*)alloc((size_t)N * 64 * 4);
    unsigned int* sA = (unsigned int*)alloc((size_t)N * 64 * 4);
    unsigned int* wb = (unsigned int*)alloc((size_t)N * 64 * 4);
    unsigned int* sb = (unsigned int*)alloc((size_t)N * 64 * 4);
    unsigned short* wbt = (unsigned short*)alloc((size_t)NCOLS * KP * 2);
    float* dis  = (float*)alloc((size_t)N * 4);
    int* off    = (int*)alloc((size_t)(N + 1) * 4);
    int* boff   = (int*)alloc((size_t)(NBK + 1) * 4);
    int* bcur   = (int*)alloc((size_t)NBK * NSUB * CPAD * 4);
    unsigned int* bkt = (unsigned int*)alloc((size_t)NBK * NSUB * BSUBCAP * 4);
    int* scol   = (int*)alloc((size_t)E * 4);
    float* Wc2t = (float*)alloc((size_t)8 * 128 * 4);
    float* s2   = (float*)alloc((size_t)N * 2 * 4);
    float* w2   = (float*)alloc((size_t)N * 2 * 4);

    hipMemsetAsync(bcur, 0, (size_t)NBK * NSUB * CPAD * 4, stream);

    int gN = (N + 255) / 256;

    // weight conversions
    k_wbt<<<(NCOLS * (KP / 8) + 255) / 256, 256, 0, stream>>>(W1, wbt);
    k_wc2t<<<4, 256, 0, stream>>>(W2, Wc2t);

    // CSR build (radix-partition bucket pass + fused emit)
    int gT = (E + TILE - 1) / TILE;
    k_bucket<<<gT, 256, 0, stream>>>(erow, ecol, bcur, bkt, E);
    k_bscan<<<1, 256, 0, stream>>>(bcur, boff, off, NBK, N, E);
    k_emit2<<<NBK, 256, 0, stream>>>(bcur, bkt, boff, off, dis, scol, N);

    // layer 1: MFMA GEMM (reads x f32 directly; XCD-local panel swizzle)
    int P = (N + 127) / 128;
    int wPerX = 3 * ((P + 7) / 8);
    k_gemm1_mfma<<<8 * wPerX, 256, 0, stream>>>(x, wbt, dis, ub, sA, wb, N, P);

    int nw4 = (N + 3) / 4;
    int gP4 = (nw4 * 64 + 255) / 256;
    // sb = bf16( sA - 2*dis^2 * prop-sum(wb) )
    k_prop_b2b<<<gP4, 256, 0, stream>>>(off, scol, wb, sA, dis, sb, N);
    // fused: h = relu(ub - dis*prop-sum(sb) + b1); out/s2/w2 = h @ W2
    k_prop_b2f_gemm2<<<gP4, 256, 0, stream>>>(off, scol, sb, ub, dis, b1,
                                              Wc2t, b2, out, s2, w2, N);

    // layer 2 props (2-wide)
    k_prop2_csr<<<gN, 256, 0, stream>>>(off, scol, w2, s2, dis, s2, 1, N);
    k_prop2_csr<<<gN, 256, 0, stream>>>(off, scol, s2, out, dis, out, 0, N);
}